// Round 1
// baseline (937.735 us; speedup 1.0000x reference)
//
#include <hip/hip_runtime.h>
#include <hip/hip_bf16.h>
#include <math.h>
#include <type_traits>

// Problem constants (reference: B=1, S=2048, H=2048, E=16, I=768, top-4, shared I=768)
#define NT 2048   // tokens
#define NH 2048   // hidden
#define NE 16     // routed experts
#define NI 768    // expert intermediate (= shared intermediate)
#define NK 4      // top-k

#define N_GUP ((long)NE * 2 * NI * NH)   // 50331648
#define N_DWN ((long)NE * NH * NI)       // 25165824
#define N_SW  ((long)NI * NH)            // 1572864

typedef __bf16 bf16_t;
typedef __attribute__((ext_vector_type(8))) __bf16 bf16x8;
typedef __attribute__((ext_vector_type(4))) __bf16 bf16x4;
typedef __attribute__((ext_vector_type(4))) float f32x4;

__device__ __forceinline__ f32x4 mfma16x16x32(bf16x8 a, bf16x8 b, f32x4 c) {
  return __builtin_amdgcn_mfma_f32_16x16x32_bf16(a, b, c, 0, 0, 0);
}

// async global->LDS DMA, 16B per lane; LDS dest = wave-uniform base + lane*16
__device__ __forceinline__ void async16(const bf16_t* g, bf16_t* l) {
  __builtin_amdgcn_global_load_lds(
      (const __attribute__((address_space(1))) void*)g,
      (__attribute__((address_space(3))) void*)l, 16, 0, 0);
}

__device__ __forceinline__ bf16x8 load8cvt(const bf16_t* p) {
  return *(const bf16x8*)p;
}
__device__ __forceinline__ bf16x8 load8cvt(const float* p) {
  float4 a = *(const float4*)p;
  float4 b = *(const float4*)(p + 4);
  bf16x8 o;
  o[0] = (bf16_t)a.x; o[1] = (bf16_t)a.y; o[2] = (bf16_t)a.z; o[3] = (bf16_t)a.w;
  o[4] = (bf16_t)b.x; o[5] = (bf16_t)b.y; o[6] = (bf16_t)b.z; o[7] = (bf16_t)b.w;
  return o;
}

// ---------------- fp32 -> bf16 conversion: all 5 weight tensors, one launch ----
__global__ __launch_bounds__(256) void k_cvt_all(
    const float* __restrict__ gup, bf16_t* __restrict__ gupb,
    const float* __restrict__ dwn, bf16_t* __restrict__ dwnb,
    const float* __restrict__ sg, bf16_t* __restrict__ sgb,
    const float* __restrict__ su, bf16_t* __restrict__ sub,
    const float* __restrict__ sd, bf16_t* __restrict__ sdb) {
  const long total = N_GUP + N_DWN + 3 * N_SW;
  long i = ((long)blockIdx.x * blockDim.x + threadIdx.x) * 8;
  long stride = (long)gridDim.x * blockDim.x * 8;
  for (; i < total; i += stride) {
    const float* s;
    bf16_t* d;
    long off = i;
    if (off < N_GUP) { s = gup; d = gupb; }
    else if ((off -= N_GUP) < N_DWN) { s = dwn; d = dwnb; }
    else if ((off -= N_DWN) < N_SW) { s = sg; d = sgb; }
    else if ((off -= N_SW) < N_SW) { s = su; d = sub; }
    else { off -= N_SW; s = sd; d = sdb; }
    *(bf16x8*)(d + off) = load8cvt(s + off);
  }
}

// ---------------- router: sigmoid + biased top-4 (+ fused x->bf16 cvt) ----------
// 4 tokens per 256-thread block (one wave per token).
__global__ __launch_bounds__(256) void k_router(const float* __restrict__ x,
                                                const float* __restrict__ rw,
                                                const float* __restrict__ eb,
                                                int* __restrict__ tki,
                                                float* __restrict__ tkw,
                                                int* __restrict__ cnt,
                                                bf16_t* __restrict__ xb) {
  int wave = threadIdx.x >> 6, lane = threadIdx.x & 63;
  int t = blockIdx.x * 4 + wave;
  const float* xr = x + (long)t * NH;
  float acc[NE];
#pragma unroll
  for (int e = 0; e < NE; ++e) acc[e] = 0.f;
  for (int it = 0; it < NH / 256; ++it) {
    int h = it * 256 + lane * 4;
    float4 xv = *(const float4*)(xr + h);
    bf16x4 xc;
    xc[0] = (bf16_t)xv.x; xc[1] = (bf16_t)xv.y; xc[2] = (bf16_t)xv.z; xc[3] = (bf16_t)xv.w;
    *(bf16x4*)(xb + (size_t)t * NH + h) = xc;
#pragma unroll
    for (int e = 0; e < NE; ++e) {
      float4 wv = *(const float4*)(rw + (long)e * NH + h);
      acc[e] += xv.x * wv.x + xv.y * wv.y + xv.z * wv.z + xv.w * wv.w;
    }
  }
#pragma unroll
  for (int e = 0; e < NE; ++e) {
    float v = acc[e];
#pragma unroll
    for (int off = 32; off > 0; off >>= 1) v += __shfl_down(v, off);
    acc[e] = v;
  }
  if (lane == 0) {
    float s[NE], b[NE];
#pragma unroll
    for (int e = 0; e < NE; ++e) {
      s[e] = 1.f / (1.f + __expf(-acc[e]));
      b[e] = s[e] + eb[e];
    }
    int sel[NK];
    float ssum = 0.f;
    unsigned used = 0;
    for (int kk = 0; kk < NK; ++kk) {
      int best = 0;
      float bv = -1e30f;
      for (int e = 0; e < NE; ++e)
        if (!((used >> e) & 1u) && b[e] > bv) { bv = b[e]; best = e; }
      used |= 1u << best;
      sel[kk] = best;
      ssum += s[best];
    }
    float inv = 1.f / (ssum + 1e-20f);
    for (int kk = 0; kk < NK; ++kk) {
      tki[t * NK + kk] = sel[kk];
      tkw[t * NK + kk] = s[sel[kk]] * inv;
      atomicAdd(cnt + sel[kk], 1);
    }
  }
}

// ---------------- exclusive scan over 16 expert counts ----------------
__global__ void k_scan(const int* __restrict__ cnt, int* __restrict__ offs) {
  if (threadIdx.x == 0) {
    int o = 0;
    for (int e = 0; e < NE; ++e) { offs[e] = o; o += cnt[e]; }
    offs[NE] = o;
  }
}

// ---------------- fill compact slot lists ----------------
__global__ __launch_bounds__(256) void k_fill(const int* __restrict__ tki,
                                              const int* __restrict__ offs,
                                              int* __restrict__ cnt2,
                                              int* __restrict__ tos,
                                              int* __restrict__ sot) {
  int t = blockIdx.x * blockDim.x + threadIdx.x;
  if (t >= NT) return;
#pragma unroll
  for (int kk = 0; kk < NK; ++kk) {
    int e = tki[t * NK + kk];
    int pos = atomicAdd(cnt2 + e, 1);
    int slot = offs[e] + pos;
    tos[slot] = t;
    sot[t * NK + kk] = slot;
  }
}

// LDS tile layout (unpadded, required by global_load_lds lane-order writes):
//   row r, chunk slot c (0..3, 8 bf16): offset r*32 + c*8 elems.
//   Source chunk at slot c is cg = c ^ ((r>>1)&3) (XOR swizzle -> <=2-way bank
//   aliasing on fragment ds_read_b128, free per m136).
//   Staging lane l (16-row wave-issue): row rb+(l>>2), slot l&3, source chunk
//   cg = (l&3) ^ ((l>>3)&3). Fragment read k-chunk lq, local row lm:
//   slot = lq ^ ((lm>>1)&3).
//
// R5 (pipeline depth): rocprof showed MfmaUtil 10%, VALUBusy 7%, HBM 14%,
// occupancy 12% -> pure latency regime. 1-deep prefetch (4KB in flight/wave)
// self-throttles delivered tile BW to ~4 TB/s (Little's law). Fix = T3/T4:
// THREE LDS buffers, TWO tiles in flight per wave, steady-state wait
// s_waitcnt vmcnt(8) (never drained to 0 mid-loop), 4->0 only in epilogue.
// LDS 48KB -> 3 blocks/CU (combined regs ~120 -> 4 waves/SIMD, LDS binds).

// ---------------- gate-up GEMM + SwiGLU epilogue ----------------
// grid: (16 Mtiles, 12 Ntiles(64), 17 groups). z=0 -> shared (largest uniform
// chunk dispatched first for tail balance); z>=1 -> expert z-1.
// act[slot][NI]: routed slots [0,4T), shared rows [4T,5T).
template <typename WT>
__global__ __launch_bounds__(256, 3) void k_gateup(
    const bf16_t* __restrict__ xb, const WT* __restrict__ gup,
    const WT* __restrict__ sg, const WT* __restrict__ su,
    const int* __restrict__ cnt, const int* __restrict__ offs,
    const int* __restrict__ tos, bf16_t* __restrict__ act) {
  __shared__ __align__(16) bf16_t As[3][128 * 32];   // 128 M-rows, 3-stage
  __shared__ __align__(16) bf16_t Bg[3][64 * 32];    // 64 N-rows (gate)
  __shared__ __align__(16) bf16_t Bu[3][64 * 32];    // 64 N-rows (up)
  int gz = blockIdx.z, tm = blockIdx.x, tn = blockIdx.y;
  int g = (gz == 0) ? NE : gz - 1;                   // shared expert first
  int cntE, slotbase;
  const WT *gp, *up;
  if (g < NE) {
    cntE = cnt[g];
    slotbase = offs[g];
    gp = gup + (size_t)g * 2 * NI * NH;
    up = gp + (size_t)NI * NH;
  } else {
    cntE = NT;
    slotbase = NK * NT;
    gp = sg;
    up = su;
  }
  int m0 = tm * 128;
  if (m0 >= cntE) return;
  int n0 = tn * 64;
  int tid = threadIdx.x;
  int wave = tid >> 6, lane = tid & 63;
  int lrow = lane >> 2;                       // 0..15 in a 16-row issue
  int cg = (lane & 3) ^ ((lane >> 3) & 3);    // swizzled source chunk

  // A staging: 8 wave-issues of 16 rows; wave w handles issues 2w, 2w+1.
  const bf16_t* a_g[2];
  bf16_t* a_l0[2];                            // buffer-0 dest; buffer b = +b*4096
#pragma unroll
  for (int j = 0; j < 2; ++j) {
    int rb = (wave * 2 + j) * 16;
    int r = rb + lrow;
    int tok;
    if (g < NE)
      tok = (m0 + r < cntE) ? tos[slotbase + m0 + r] : 0;
    else
      tok = m0 + r;
    a_g[j] = xb + (size_t)tok * NH + cg * 8;
    a_l0[j] = As[0] + rb * 32;
  }
  // B staging: 2 matrices x 4 issues = 8; wave w handles issues 2w, 2w+1.
  const WT* b_g[2];
  bf16_t* b_l0[2];                            // buffer b = +b*2048
#pragma unroll
  for (int j = 0; j < 2; ++j) {
    int idx = wave * 2 + j;
    int mat = idx >> 2;
    int rb = (idx & 3) * 16;
    int r = rb + lrow;
    b_g[j] = (mat ? up : gp) + (size_t)(n0 + r) * NH + cg * 8;
    b_l0[j] = (mat ? Bu[0] : Bg[0]) + rb * 32;
  }

  f32x4 zero = {0.f, 0.f, 0.f, 0.f};
  f32x4 accg[4][2], accu[4][2];
#pragma unroll
  for (int mi = 0; mi < 4; ++mi)
#pragma unroll
    for (int ni = 0; ni < 2; ++ni) {
      accg[mi][ni] = zero;
      accu[mi][ni] = zero;
    }
  int wm = (wave >> 1) * 64, wn = (wave & 1) * 32;
  int lm = lane & 15, lq = lane >> 4;
  int slot8 = (lq ^ ((lm >> 1) & 3)) * 8;     // fragment-read chunk slot
  const int KT = NH / 32;

  if constexpr (std::is_same<WT, bf16_t>::value) {
    // prologue: tiles 0,1 -> buffers 0,1 (8 loads/wave in flight)
#pragma unroll
    for (int j = 0; j < 2; ++j) async16(a_g[j], a_l0[j]);
#pragma unroll
    for (int j = 0; j < 2; ++j) async16(b_g[j], b_l0[j]);
#pragma unroll
    for (int j = 0; j < 2; ++j) async16(a_g[j] + 32, a_l0[j] + 4096);
#pragma unroll
    for (int j = 0; j < 2; ++j) async16(b_g[j] + 32, b_l0[j] + 2048);
    int cur = 0, nb = 2;                      // buffer rotation
    for (int kt = 0; kt < KT; ++kt) {
      int curoA = cur * 4096, curoB = cur * 2048;
      if (kt + 2 < KT) {
        int koff = (kt + 2) * 32;
        int nA = nb * 4096, nB = nb * 2048;
#pragma unroll
        for (int j = 0; j < 2; ++j) async16(a_g[j] + koff, a_l0[j] + nA);
#pragma unroll
        for (int j = 0; j < 2; ++j) async16(b_g[j] + koff, b_l0[j] + nB);
        // tiles kt+1, kt+2 (8 loads) stay in flight across the barrier
        asm volatile("s_waitcnt vmcnt(8)" ::: "memory");
      } else if (kt + 1 < KT) {
        asm volatile("s_waitcnt vmcnt(4)" ::: "memory");
      } else {
        asm volatile("s_waitcnt vmcnt(0)" ::: "memory");
      }
      asm volatile("s_barrier" ::: "memory");  // all waves' tile-kt loads landed
      bf16x8 af[4], bg[2], bu[2];
#pragma unroll
      for (int mi = 0; mi < 4; ++mi)
        af[mi] = *(const bf16x8*)(As[0] + curoA + (wm + mi * 16 + lm) * 32 + slot8);
#pragma unroll
      for (int ni = 0; ni < 2; ++ni) {
        bg[ni] = *(const bf16x8*)(Bg[0] + curoB + (wn + ni * 16 + lm) * 32 + slot8);
        bu[ni] = *(const bf16x8*)(Bu[0] + curoB + (wn + ni * 16 + lm) * 32 + slot8);
      }
#pragma unroll
      for (int mi = 0; mi < 4; ++mi)
#pragma unroll
        for (int ni = 0; ni < 2; ++ni) {
          accg[mi][ni] = mfma16x16x32(af[mi], bg[ni], accg[mi][ni]);
          accu[mi][ni] = mfma16x16x32(af[mi], bu[ni], accu[mi][ni]);
        }
      // readers done before tile kt+3 (issued next iter) overwrites buf cur
      asm volatile("s_barrier" ::: "memory");
      cur = (cur == 2) ? 0 : cur + 1;
      nb = (nb == 2) ? 0 : nb + 1;
    }
  } else {
    // fp32-weight fallback: single-buffered, register staging for B
    for (int kt = 0; kt < KT; ++kt) {
      if (kt) __syncthreads();
      int koff = kt * 32;
#pragma unroll
      for (int j = 0; j < 2; ++j) async16(a_g[j] + koff, a_l0[j]);
#pragma unroll
      for (int j = 0; j < 2; ++j)
        *(bf16x8*)(b_l0[j] + lane * 8) = load8cvt(b_g[j] + koff);
      __syncthreads();
      bf16x8 af[4], bg[2], bu[2];
#pragma unroll
      for (int mi = 0; mi < 4; ++mi)
        af[mi] = *(const bf16x8*)(As[0] + (wm + mi * 16 + lm) * 32 + slot8);
#pragma unroll
      for (int ni = 0; ni < 2; ++ni) {
        bg[ni] = *(const bf16x8*)(Bg[0] + (wn + ni * 16 + lm) * 32 + slot8);
        bu[ni] = *(const bf16x8*)(Bu[0] + (wn + ni * 16 + lm) * 32 + slot8);
      }
#pragma unroll
      for (int mi = 0; mi < 4; ++mi)
#pragma unroll
        for (int ni = 0; ni < 2; ++ni) {
          accg[mi][ni] = mfma16x16x32(af[mi], bg[ni], accg[mi][ni]);
          accu[mi][ni] = mfma16x16x32(af[mi], bu[ni], accu[mi][ni]);
        }
    }
  }
  // SwiGLU epilogue: act = silu(g) * u   (C/D layout: col=lane&15, row=quad*4+reg)
#pragma unroll
  for (int mi = 0; mi < 4; ++mi) {
#pragma unroll
    for (int r = 0; r < 4; ++r) {
      int row = wm + mi * 16 + lq * 4 + r;
      if (m0 + row >= cntE) continue;
      size_t obase = (size_t)(slotbase + m0 + row) * NI + n0 + wn;
#pragma unroll
      for (int ni = 0; ni < 2; ++ni) {
        float gv = accg[mi][ni][r];
        float uv = accu[mi][ni][r];
        float a = gv / (1.f + __expf(-gv)) * uv;
        act[obase + ni * 16 + lm] = (bf16_t)a;
      }
    }
  }
}

// ---------------- down GEMM ----------------
// grid: (16 Mtiles, 16 Ntiles, 17 groups). Writes dout[slot][NH] (bf16), unweighted.
template <typename WT>
__global__ __launch_bounds__(256, 3) void k_down(
    const bf16_t* __restrict__ act, const WT* __restrict__ dwn,
    const WT* __restrict__ sd, const int* __restrict__ cnt,
    const int* __restrict__ offs, bf16_t* __restrict__ dout) {
  __shared__ __align__(16) bf16_t As[3][128 * 32];
  __shared__ __align__(16) bf16_t Bs[3][128 * 32];
  int gz = blockIdx.z, tm = blockIdx.x, tn = blockIdx.y;
  int g = (gz == 0) ? NE : gz - 1;                   // shared expert first
  int cntE, slotbase;
  const WT* wp;
  if (g < NE) {
    cntE = cnt[g];
    slotbase = offs[g];
    wp = dwn + (size_t)g * NH * NI;
  } else {
    cntE = NT;
    slotbase = NK * NT;
    wp = sd;
  }
  int m0 = tm * 128;
  if (m0 >= cntE) return;
  int n0 = tn * 128;
  int tid = threadIdx.x;
  int wave = tid >> 6, lane = tid & 63;
  int lrow = lane >> 2;
  int cg = (lane & 3) ^ ((lane >> 3) & 3);

  const bf16_t* a_g[2];
  bf16_t* a_l0[2];
  const WT* b_g[2];
  bf16_t* b_l0[2];
#pragma unroll
  for (int j = 0; j < 2; ++j) {
    int rb = (wave * 2 + j) * 16;
    int r = rb + lrow;
    a_g[j] = act + (size_t)(slotbase + m0 + r) * NI + cg * 8;
    a_l0[j] = As[0] + rb * 32;
    b_g[j] = wp + (size_t)(n0 + r) * NI + cg * 8;
    b_l0[j] = Bs[0] + rb * 32;
  }
  f32x4 zero = {0.f, 0.f, 0.f, 0.f};
  f32x4 acc[4][4];
#pragma unroll
  for (int mi = 0; mi < 4; ++mi)
#pragma unroll
    for (int ni = 0; ni < 4; ++ni) acc[mi][ni] = zero;
  int wm = (wave >> 1) * 64, wn = (wave & 1) * 64;
  int lm = lane & 15, lq = lane >> 4;
  int slot8 = (lq ^ ((lm >> 1) & 3)) * 8;
  const int KT = NI / 32;

  if constexpr (std::is_same<WT, bf16_t>::value) {
    // prologue: tiles 0,1 -> buffers 0,1
#pragma unroll
    for (int j = 0; j < 2; ++j) async16(a_g[j], a_l0[j]);
#pragma unroll
    for (int j = 0; j < 2; ++j) async16(b_g[j], b_l0[j]);
#pragma unroll
    for (int j = 0; j < 2; ++j) async16(a_g[j] + 32, a_l0[j] + 4096);
#pragma unroll
    for (int j = 0; j < 2; ++j) async16(b_g[j] + 32, b_l0[j] + 4096);
    int cur = 0, nb = 2;
    for (int kt = 0; kt < KT; ++kt) {
      int curo = cur * 4096;
      if (kt + 2 < KT) {
        int koff = (kt + 2) * 32;
        int nA = nb * 4096;
#pragma unroll
        for (int j = 0; j < 2; ++j) async16(a_g[j] + koff, a_l0[j] + nA);
#pragma unroll
        for (int j = 0; j < 2; ++j) async16(b_g[j] + koff, b_l0[j] + nA);
        asm volatile("s_waitcnt vmcnt(8)" ::: "memory");
      } else if (kt + 1 < KT) {
        asm volatile("s_waitcnt vmcnt(4)" ::: "memory");
      } else {
        asm volatile("s_waitcnt vmcnt(0)" ::: "memory");
      }
      asm volatile("s_barrier" ::: "memory");
      bf16x8 af[4], bf[4];
#pragma unroll
      for (int mi = 0; mi < 4; ++mi)
        af[mi] = *(const bf16x8*)(As[0] + curo + (wm + mi * 16 + lm) * 32 + slot8);
#pragma unroll
      for (int ni = 0; ni < 4; ++ni)
        bf[ni] = *(const bf16x8*)(Bs[0] + curo + (wn + ni * 16 + lm) * 32 + slot8);
#pragma unroll
      for (int mi = 0; mi < 4; ++mi)
#pragma unroll
        for (int ni = 0; ni < 4; ++ni)
          acc[mi][ni] = mfma16x16x32(af[mi], bf[ni], acc[mi][ni]);
      asm volatile("s_barrier" ::: "memory");
      cur = (cur == 2) ? 0 : cur + 1;
      nb = (nb == 2) ? 0 : nb + 1;
    }
  } else {
    for (int kt = 0; kt < KT; ++kt) {
      if (kt) __syncthreads();
      int koff = kt * 32;
#pragma unroll
      for (int j = 0; j < 2; ++j) async16(a_g[j] + koff, a_l0[j]);
#pragma unroll
      for (int j = 0; j < 2; ++j)
        *(bf16x8*)(b_l0[j] + lane * 8) = load8cvt(b_g[j] + koff);
      __syncthreads();
      bf16x8 af[4], bf[4];
#pragma unroll
      for (int mi = 0; mi < 4; ++mi)
        af[mi] = *(const bf16x8*)(As[0] + (wm + mi * 16 + lm) * 32 + slot8);
#pragma unroll
      for (int ni = 0; ni < 4; ++ni)
        bf[ni] = *(const bf16x8*)(Bs[0] + (wn + ni * 16 + lm) * 32 + slot8);
#pragma unroll
      for (int mi = 0; mi < 4; ++mi)
#pragma unroll
        for (int ni = 0; ni < 4; ++ni)
          acc[mi][ni] = mfma16x16x32(af[mi], bf[ni], acc[mi][ni]);
    }
  }
#pragma unroll
  for (int mi = 0; mi < 4; ++mi) {
#pragma unroll
    for (int r = 0; r < 4; ++r) {
      int row = wm + mi * 16 + lq * 4 + r;
      if (m0 + row >= cntE) continue;
      size_t obase = (size_t)(slotbase + m0 + row) * NH + n0 + wn;
#pragma unroll
      for (int ni = 0; ni < 4; ++ni)
        dout[obase + ni * 16 + lm] = (bf16_t)acc[mi][ni][r];
    }
  }
}

// ---------------- combine: weighted sum of 4 routed slots + shared ----------------
__global__ __launch_bounds__(256) void k_combine(const bf16_t* __restrict__ dout,
                                                 const int* __restrict__ sot,
                                                 const float* __restrict__ tkw,
                                                 float* __restrict__ out) {
  int t = blockIdx.x;
  int h0 = threadIdx.x * 8;
  int s0 = sot[t * 4 + 0], s1 = sot[t * 4 + 1], s2 = sot[t * 4 + 2], s3 = sot[t * 4 + 3];
  float w0 = tkw[t * 4 + 0], w1 = tkw[t * 4 + 1], w2 = tkw[t * 4 + 2], w3 = tkw[t * 4 + 3];
  bf16x8 v0 = *(const bf16x8*)(dout + (size_t)s0 * NH + h0);
  bf16x8 v1 = *(const bf16x8*)(dout + (size_t)s1 * NH + h0);
  bf16x8 v2 = *(const bf16x8*)(dout + (size_t)s2 * NH + h0);
  bf16x8 v3 = *(const bf16x8*)(dout + (size_t)s3 * NH + h0);
  bf16x8 vs = *(const bf16x8*)(dout + (size_t)(NK * NT + t) * NH + h0);
  float o[8];
#pragma unroll
  for (int j = 0; j < 8; ++j)
    o[j] = w0 * (float)v0[j] + w1 * (float)v1[j] + w2 * (float)v2[j] +
           w3 * (float)v3[j] + (float)vs[j];
  float* op = out + (size_t)t * NH + h0;
  *(float4*)op = make_float4(o[0], o[1], o[2], o[3]);
  *(float4*)(op + 4) = make_float4(o[4], o[5], o[6], o[7]);
}

// ---------------- host launcher ----------------
extern "C" void kernel_launch(void* const* d_in, const int* in_sizes, int n_in,
                              void* d_out, int out_size, void* d_ws, size_t ws_size,
                              hipStream_t stream) {
  const float* x   = (const float*)d_in[0];
  const float* rw  = (const float*)d_in[1];
  const float* eb  = (const float*)d_in[2];
  const float* gup = (const float*)d_in[3];
  const float* dwn = (const float*)d_in[4];
  const float* sg  = (const float*)d_in[5];
  const float* su  = (const float*)d_in[6];
  const float* sd  = (const float*)d_in[7];
  float* out = (float*)d_out;

  char* ws = (char*)d_ws;
  size_t off = 0;
  auto alloc = [&](size_t b) {
    size_t p = off;
    off = (off + b + 255) & ~(size_t)255;
    return p;
  };
  int*    cnt  = (int*)(ws + alloc(NE * 4));
  int*    cnt2 = (int*)(ws + alloc(NE * 4));
  int*    offs = (int*)(ws + alloc((NE + 1) * 4));
  int*    tki  = (int*)(ws + alloc((size_t)NT * NK * 4));
  float*  tkw  = (float*)(ws + alloc((size_t)NT * NK * 4));
  int*    tos  = (int*)(ws + alloc((size_t)NK * NT * 4));
  int*    sot  = (int*)(ws + alloc((size_t)NT * NK * 4));
  bf16_t* xb   = (bf16_t*)(ws + alloc((size_t)NT * NH * 2));
  bf16_t* act  = (bf16_t*)(ws + alloc((size_t)(NK + 1) * NT * NI * 2));
  bf16_t* dob  = (bf16_t*)(ws + alloc((size_t)(NK + 1) * NT * NH * 2));

  bool tierA = (off + (N_GUP + N_DWN + 3 * N_SW) * 2 + 2048) <= ws_size;
  bf16_t *gupb = nullptr, *dwnb = nullptr, *sgb = nullptr, *sub = nullptr, *sdb = nullptr;
  if (tierA) {
    gupb = (bf16_t*)(ws + alloc(N_GUP * 2));
    dwnb = (bf16_t*)(ws + alloc(N_DWN * 2));
    sgb  = (bf16_t*)(ws + alloc(N_SW * 2));
    sub  = (bf16_t*)(ws + alloc(N_SW * 2));
    sdb  = (bf16_t*)(ws + alloc(N_SW * 2));
  }

  hipMemsetAsync(cnt, 0, NE * 4, stream);
  hipMemsetAsync(cnt2, 0, NE * 4, stream);

  if (tierA) {
    long total_vec = (N_GUP + N_DWN + 3 * N_SW) / 8;
    int blocks = (int)((total_vec + 255) / 256);
    k_cvt_all<<<blocks, 256, 0, stream>>>(gup, gupb, dwn, dwnb, sg, sgb, su, sub, sd, sdb);
  }

  k_router<<<NT / 4, 256, 0, stream>>>(x, rw, eb, tki, tkw, cnt, xb);
  k_scan<<<1, 64, 0, stream>>>(cnt, offs);
  k_fill<<<NT / 256, 256, 0, stream>>>(tki, offs, cnt2, tos, sot);

  dim3 gu_grid(16, NI / 64, NE + 1);
  dim3 dn_grid(16, NH / 128, NE + 1);
  if (tierA) {
    k_gateup<bf16_t><<<gu_grid, 256, 0, stream>>>(xb, gupb, sgb, sub, cnt, offs, tos, act);
    k_down<bf16_t><<<dn_grid, 256, 0, stream>>>(act, dwnb, sdb, cnt, offs, dob);
  } else {
    k_gateup<float><<<gu_grid, 256, 0, stream>>>(xb, gup, sg, su, cnt, offs, tos, act);
    k_down<float><<<dn_grid, 256, 0, stream>>>(act, dwn, sd, cnt, offs, dob);
  }

  k_combine<<<NT, 256, 0, stream>>>(dob, sot, tkw, out);
}

// Round 2
// 734.064 us; speedup vs baseline: 1.2775x; 1.2775x over previous
//
#include <hip/hip_runtime.h>
#include <hip/hip_bf16.h>
#include <math.h>
#include <type_traits>

// Problem constants (reference: B=1, S=2048, H=2048, E=16, I=768, top-4, shared I=768)
#define NT 2048   // tokens
#define NH 2048   // hidden
#define NE 16     // routed experts
#define NI 768    // expert intermediate (= shared intermediate)
#define NK 4      // top-k

#define N_GUP ((long)NE * 2 * NI * NH)   // 50331648
#define N_DWN ((long)NE * NH * NI)       // 25165824
#define N_SW  ((long)NI * NH)            // 1572864

typedef __bf16 bf16_t;
typedef __attribute__((ext_vector_type(8))) __bf16 bf16x8;
typedef __attribute__((ext_vector_type(4))) __bf16 bf16x4;
typedef __attribute__((ext_vector_type(4))) float f32x4;

__device__ __forceinline__ f32x4 mfma16x16x32(bf16x8 a, bf16x8 b, f32x4 c) {
  return __builtin_amdgcn_mfma_f32_16x16x32_bf16(a, b, c, 0, 0, 0);
}

// async global->LDS DMA, 16B per lane; LDS dest = wave-uniform base + lane*16
__device__ __forceinline__ void async16(const bf16_t* g, bf16_t* l) {
  __builtin_amdgcn_global_load_lds(
      (const __attribute__((address_space(1))) void*)g,
      (__attribute__((address_space(3))) void*)l, 16, 0, 0);
}

__device__ __forceinline__ bf16x8 load8cvt(const bf16_t* p) {
  return *(const bf16x8*)p;
}
__device__ __forceinline__ bf16x8 load8cvt(const float* p) {
  float4 a = *(const float4*)p;
  float4 b = *(const float4*)(p + 4);
  bf16x8 o;
  o[0] = (bf16_t)a.x; o[1] = (bf16_t)a.y; o[2] = (bf16_t)a.z; o[3] = (bf16_t)a.w;
  o[4] = (bf16_t)b.x; o[5] = (bf16_t)b.y; o[6] = (bf16_t)b.z; o[7] = (bf16_t)b.w;
  return o;
}

// ---------------- fp32 -> bf16 conversion: all 5 weight tensors, one launch ----
__global__ __launch_bounds__(256) void k_cvt_all(
    const float* __restrict__ gup, bf16_t* __restrict__ gupb,
    const float* __restrict__ dwn, bf16_t* __restrict__ dwnb,
    const float* __restrict__ sg, bf16_t* __restrict__ sgb,
    const float* __restrict__ su, bf16_t* __restrict__ sub,
    const float* __restrict__ sd, bf16_t* __restrict__ sdb) {
  const long total = N_GUP + N_DWN + 3 * N_SW;
  long i = ((long)blockIdx.x * blockDim.x + threadIdx.x) * 8;
  long stride = (long)gridDim.x * blockDim.x * 8;
  for (; i < total; i += stride) {
    const float* s;
    bf16_t* d;
    long off = i;
    if (off < N_GUP) { s = gup; d = gupb; }
    else if ((off -= N_GUP) < N_DWN) { s = dwn; d = dwnb; }
    else if ((off -= N_DWN) < N_SW) { s = sg; d = sgb; }
    else if ((off -= N_SW) < N_SW) { s = su; d = sub; }
    else { off -= N_SW; s = sd; d = sdb; }
    *(bf16x8*)(d + off) = load8cvt(s + off);
  }
}

// ---------------- router: sigmoid + biased top-4 (+ fused x->bf16 cvt) ----------
// 4 tokens per 256-thread block (one wave per token).
__global__ __launch_bounds__(256) void k_router(const float* __restrict__ x,
                                                const float* __restrict__ rw,
                                                const float* __restrict__ eb,
                                                int* __restrict__ tki,
                                                float* __restrict__ tkw,
                                                int* __restrict__ cnt,
                                                bf16_t* __restrict__ xb) {
  int wave = threadIdx.x >> 6, lane = threadIdx.x & 63;
  int t = blockIdx.x * 4 + wave;
  const float* xr = x + (long)t * NH;
  float acc[NE];
#pragma unroll
  for (int e = 0; e < NE; ++e) acc[e] = 0.f;
  for (int it = 0; it < NH / 256; ++it) {
    int h = it * 256 + lane * 4;
    float4 xv = *(const float4*)(xr + h);
    bf16x4 xc;
    xc[0] = (bf16_t)xv.x; xc[1] = (bf16_t)xv.y; xc[2] = (bf16_t)xv.z; xc[3] = (bf16_t)xv.w;
    *(bf16x4*)(xb + (size_t)t * NH + h) = xc;
#pragma unroll
    for (int e = 0; e < NE; ++e) {
      float4 wv = *(const float4*)(rw + (long)e * NH + h);
      acc[e] += xv.x * wv.x + xv.y * wv.y + xv.z * wv.z + xv.w * wv.w;
    }
  }
#pragma unroll
  for (int e = 0; e < NE; ++e) {
    float v = acc[e];
#pragma unroll
    for (int off = 32; off > 0; off >>= 1) v += __shfl_down(v, off);
    acc[e] = v;
  }
  if (lane == 0) {
    float s[NE], b[NE];
#pragma unroll
    for (int e = 0; e < NE; ++e) {
      s[e] = 1.f / (1.f + __expf(-acc[e]));
      b[e] = s[e] + eb[e];
    }
    int sel[NK];
    float ssum = 0.f;
    unsigned used = 0;
    for (int kk = 0; kk < NK; ++kk) {
      int best = 0;
      float bv = -1e30f;
      for (int e = 0; e < NE; ++e)
        if (!((used >> e) & 1u) && b[e] > bv) { bv = b[e]; best = e; }
      used |= 1u << best;
      sel[kk] = best;
      ssum += s[best];
    }
    float inv = 1.f / (ssum + 1e-20f);
    for (int kk = 0; kk < NK; ++kk) {
      tki[t * NK + kk] = sel[kk];
      tkw[t * NK + kk] = s[sel[kk]] * inv;
      atomicAdd(cnt + sel[kk], 1);
    }
  }
}

// ---------------- exclusive scan over 16 expert counts ----------------
__global__ void k_scan(const int* __restrict__ cnt, int* __restrict__ offs) {
  if (threadIdx.x == 0) {
    int o = 0;
    for (int e = 0; e < NE; ++e) { offs[e] = o; o += cnt[e]; }
    offs[NE] = o;
  }
}

// ---------------- fill compact slot lists ----------------
__global__ __launch_bounds__(256) void k_fill(const int* __restrict__ tki,
                                              const int* __restrict__ offs,
                                              int* __restrict__ cnt2,
                                              int* __restrict__ tos,
                                              int* __restrict__ sot) {
  int t = blockIdx.x * blockDim.x + threadIdx.x;
  if (t >= NT) return;
#pragma unroll
  for (int kk = 0; kk < NK; ++kk) {
    int e = tki[t * NK + kk];
    int pos = atomicAdd(cnt2 + e, 1);
    int slot = offs[e] + pos;
    tos[slot] = t;
    sot[t * NK + kk] = slot;
  }
}

// LDS tile layout (unpadded, required by global_load_lds lane-order writes):
//   row r, chunk slot c (0..3, 8 bf16): offset r*32 + c*8 elems.
//   Source chunk at slot c is cg = c ^ ((r>>1)&3) (XOR swizzle -> <=2-way bank
//   aliasing on fragment ds_read_b128, free per m136).
//   Staging lane l (16-row wave-issue): row rb+(l>>2), slot l&3, source chunk
//   cg = (l&3) ^ ((l>>3)&3). Fragment read k-chunk lq, local row lm:
//   slot = lq ^ ((lm>>1)&3).
//
// R6 (XCD work remap): R5's depth-2 pipeline was NEUTRAL -> limiter is not
// per-wave in-flight bytes; the memory system saturates at ~3.5 TB/s for this
// pattern because B-panel consumers (same expert/tn, different tm) are
// CONSECUTIVE blockIdx -> round-robin to 8 DIFFERENT XCDs -> every panel read
// is an L2 miss (L3/HBM, ~600-900cy) instead of an L2 hit (~200cy).
// Fix = bijective chunked XCD remap (T1/m204): flat -> w=(flat%8)*per+flat/8,
// work order tm fastest, then expert z, then tn. Panel consumers land in the
// same per-XCD chunk back-to-back; each XCD still sees all 17 groups (balance).
// Pipeline reverted to the proven 2-stage / vmcnt(4) (32 KB LDS).

// ---------------- gate-up GEMM + SwiGLU epilogue ----------------
// grid: 16*12*17 blocks (flat). work w: tm = w%16, z = (w/16)%17, tn = w/272.
// z=0 -> shared expert; z>=1 -> routed expert z-1.
// act[slot][NI]: routed slots [0,4T), shared rows [4T,5T).
template <typename WT>
__global__ __launch_bounds__(256, 2) void k_gateup(
    const bf16_t* __restrict__ xb, const WT* __restrict__ gup,
    const WT* __restrict__ sg, const WT* __restrict__ su,
    const int* __restrict__ cnt, const int* __restrict__ offs,
    const int* __restrict__ tos, bf16_t* __restrict__ act) {
  __shared__ __align__(16) bf16_t As[2][128 * 32];   // 128 M-rows
  __shared__ __align__(16) bf16_t Bg[2][64 * 32];    // 64 N-rows (gate)
  __shared__ __align__(16) bf16_t Bu[2][64 * 32];    // 64 N-rows (up)
  // --- bijective chunked XCD remap (total = 3264 = 8 * 408) ---
  int flat = blockIdx.x + gridDim.x * (blockIdx.y + gridDim.y * blockIdx.z);
  int w = (flat & 7) * 408 + (flat >> 3);
  int tm = w & 15;
  int zz = (w >> 4) % 17;
  int tn = w / 272;
  int g = (zz == 0) ? NE : zz - 1;                   // shared expert first in-chunk
  int cntE, slotbase;
  const WT *gp, *up;
  if (g < NE) {
    cntE = cnt[g];
    slotbase = offs[g];
    gp = gup + (size_t)g * 2 * NI * NH;
    up = gp + (size_t)NI * NH;
  } else {
    cntE = NT;
    slotbase = NK * NT;
    gp = sg;
    up = su;
  }
  int m0 = tm * 128;
  if (m0 >= cntE) return;
  int n0 = tn * 64;
  int tid = threadIdx.x;
  int wave = tid >> 6, lane = tid & 63;
  int lrow = lane >> 2;                       // 0..15 in a 16-row issue
  int cg = (lane & 3) ^ ((lane >> 3) & 3);    // swizzled source chunk

  // A staging: 8 wave-issues of 16 rows; wave w handles issues 2w, 2w+1.
  const bf16_t* a_g[2];
  bf16_t* a_l0[2];                            // buffer-0 dest; buffer 1 = +4096
#pragma unroll
  for (int j = 0; j < 2; ++j) {
    int rb = (wave * 2 + j) * 16;
    int r = rb + lrow;
    int tok;
    if (g < NE)
      tok = (m0 + r < cntE) ? tos[slotbase + m0 + r] : 0;
    else
      tok = m0 + r;
    a_g[j] = xb + (size_t)tok * NH + cg * 8;
    a_l0[j] = As[0] + rb * 32;
  }
  // B staging: 2 matrices x 4 issues = 8; wave w handles issues 2w, 2w+1.
  const WT* b_g[2];
  bf16_t* b_l0[2];                            // buffer 1 = +2048
#pragma unroll
  for (int j = 0; j < 2; ++j) {
    int idx = wave * 2 + j;
    int mat = idx >> 2;
    int rb = (idx & 3) * 16;
    int r = rb + lrow;
    b_g[j] = (mat ? up : gp) + (size_t)(n0 + r) * NH + cg * 8;
    b_l0[j] = (mat ? Bu[0] : Bg[0]) + rb * 32;
  }

  f32x4 zero = {0.f, 0.f, 0.f, 0.f};
  f32x4 accg[4][2], accu[4][2];
#pragma unroll
  for (int mi = 0; mi < 4; ++mi)
#pragma unroll
    for (int ni = 0; ni < 2; ++ni) {
      accg[mi][ni] = zero;
      accu[mi][ni] = zero;
    }
  int wm = (wave >> 1) * 64, wn = (wave & 1) * 32;
  int lm = lane & 15, lq = lane >> 4;
  int slot8 = (lq ^ ((lm >> 1) & 3)) * 8;     // fragment-read chunk slot
  const int KT = NH / 32;

  if constexpr (std::is_same<WT, bf16_t>::value) {
    // prologue: tile 0 -> buffer 0
#pragma unroll
    for (int j = 0; j < 2; ++j) async16(a_g[j], a_l0[j]);
#pragma unroll
    for (int j = 0; j < 2; ++j) async16(b_g[j], b_l0[j]);
    for (int kt = 0; kt < KT; ++kt) {
      int cur = kt & 1, nxt = cur ^ 1;
      int curoA = cur * 4096, curoB = cur * 2048;
      if (kt + 1 < KT) {
        int koff = (kt + 1) * 32;
        int nxtoA = nxt * 4096, nxtoB = nxt * 2048;
#pragma unroll
        for (int j = 0; j < 2; ++j) async16(a_g[j] + koff, a_l0[j] + nxtoA);
#pragma unroll
        for (int j = 0; j < 2; ++j) async16(b_g[j] + koff, b_l0[j] + nxtoB);
        asm volatile("s_waitcnt vmcnt(4)" ::: "memory");  // tile kt landed; kt+1 in flight
      } else {
        asm volatile("s_waitcnt vmcnt(0)" ::: "memory");
      }
      asm volatile("s_barrier" ::: "memory");
      bf16x8 af[4], bg[2], bu[2];
#pragma unroll
      for (int mi = 0; mi < 4; ++mi)
        af[mi] = *(const bf16x8*)(As[0] + curoA + (wm + mi * 16 + lm) * 32 + slot8);
#pragma unroll
      for (int ni = 0; ni < 2; ++ni) {
        bg[ni] = *(const bf16x8*)(Bg[0] + curoB + (wn + ni * 16 + lm) * 32 + slot8);
        bu[ni] = *(const bf16x8*)(Bu[0] + curoB + (wn + ni * 16 + lm) * 32 + slot8);
      }
#pragma unroll
      for (int mi = 0; mi < 4; ++mi)
#pragma unroll
        for (int ni = 0; ni < 2; ++ni) {
          accg[mi][ni] = mfma16x16x32(af[mi], bg[ni], accg[mi][ni]);
          accu[mi][ni] = mfma16x16x32(af[mi], bu[ni], accu[mi][ni]);
        }
      asm volatile("s_barrier" ::: "memory");  // readers done before kt+2 overwrites cur
    }
  } else {
    // fp32-weight fallback: single-buffered, register staging for B
    for (int kt = 0; kt < KT; ++kt) {
      if (kt) __syncthreads();
      int koff = kt * 32;
#pragma unroll
      for (int j = 0; j < 2; ++j) async16(a_g[j] + koff, a_l0[j]);
#pragma unroll
      for (int j = 0; j < 2; ++j)
        *(bf16x8*)(b_l0[j] + lane * 8) = load8cvt(b_g[j] + koff);
      __syncthreads();
      bf16x8 af[4], bg[2], bu[2];
#pragma unroll
      for (int mi = 0; mi < 4; ++mi)
        af[mi] = *(const bf16x8*)(As[0] + (wm + mi * 16 + lm) * 32 + slot8);
#pragma unroll
      for (int ni = 0; ni < 2; ++ni) {
        bg[ni] = *(const bf16x8*)(Bg[0] + (wn + ni * 16 + lm) * 32 + slot8);
        bu[ni] = *(const bf16x8*)(Bu[0] + (wn + ni * 16 + lm) * 32 + slot8);
      }
#pragma unroll
      for (int mi = 0; mi < 4; ++mi)
#pragma unroll
        for (int ni = 0; ni < 2; ++ni) {
          accg[mi][ni] = mfma16x16x32(af[mi], bg[ni], accg[mi][ni]);
          accu[mi][ni] = mfma16x16x32(af[mi], bu[ni], accu[mi][ni]);
        }
    }
  }
  // SwiGLU epilogue: act = silu(g) * u   (C/D layout: col=lane&15, row=quad*4+reg)
#pragma unroll
  for (int mi = 0; mi < 4; ++mi) {
#pragma unroll
    for (int r = 0; r < 4; ++r) {
      int row = wm + mi * 16 + lq * 4 + r;
      if (m0 + row >= cntE) continue;
      size_t obase = (size_t)(slotbase + m0 + row) * NI + n0 + wn;
#pragma unroll
      for (int ni = 0; ni < 2; ++ni) {
        float gv = accg[mi][ni][r];
        float uv = accu[mi][ni][r];
        float a = gv / (1.f + __expf(-gv)) * uv;
        act[obase + ni * 16 + lm] = (bf16_t)a;
      }
    }
  }
}

// ---------------- down GEMM ----------------
// grid: 16*16*17 blocks (flat). w: tm = w%16, z = (w/16)%17, tn = w/272.
// Writes dout[slot][NH] (bf16), unweighted.
template <typename WT>
__global__ __launch_bounds__(256, 2) void k_down(
    const bf16_t* __restrict__ act, const WT* __restrict__ dwn,
    const WT* __restrict__ sd, const int* __restrict__ cnt,
    const int* __restrict__ offs, bf16_t* __restrict__ dout) {
  __shared__ __align__(16) bf16_t As[2][128 * 32];
  __shared__ __align__(16) bf16_t Bs[2][128 * 32];
  // --- bijective chunked XCD remap (total = 4352 = 8 * 544) ---
  int flat = blockIdx.x + gridDim.x * (blockIdx.y + gridDim.y * blockIdx.z);
  int w = (flat & 7) * 544 + (flat >> 3);
  int tm = w & 15;
  int zz = (w >> 4) % 17;
  int tn = w / 272;
  int g = (zz == 0) ? NE : zz - 1;
  int cntE, slotbase;
  const WT* wp;
  if (g < NE) {
    cntE = cnt[g];
    slotbase = offs[g];
    wp = dwn + (size_t)g * NH * NI;
  } else {
    cntE = NT;
    slotbase = NK * NT;
    wp = sd;
  }
  int m0 = tm * 128;
  if (m0 >= cntE) return;
  int n0 = tn * 128;
  int tid = threadIdx.x;
  int wave = tid >> 6, lane = tid & 63;
  int lrow = lane >> 2;
  int cg = (lane & 3) ^ ((lane >> 3) & 3);

  const bf16_t* a_g[2];
  bf16_t* a_l0[2];
  const WT* b_g[2];
  bf16_t* b_l0[2];
#pragma unroll
  for (int j = 0; j < 2; ++j) {
    int rb = (wave * 2 + j) * 16;
    int r = rb + lrow;
    a_g[j] = act + (size_t)(slotbase + m0 + r) * NI + cg * 8;
    a_l0[j] = As[0] + rb * 32;
    b_g[j] = wp + (size_t)(n0 + r) * NI + cg * 8;
    b_l0[j] = Bs[0] + rb * 32;
  }
  f32x4 zero = {0.f, 0.f, 0.f, 0.f};
  f32x4 acc[4][4];
#pragma unroll
  for (int mi = 0; mi < 4; ++mi)
#pragma unroll
    for (int ni = 0; ni < 4; ++ni) acc[mi][ni] = zero;
  int wm = (wave >> 1) * 64, wn = (wave & 1) * 64;
  int lm = lane & 15, lq = lane >> 4;
  int slot8 = (lq ^ ((lm >> 1) & 3)) * 8;
  const int KT = NI / 32;

  if constexpr (std::is_same<WT, bf16_t>::value) {
#pragma unroll
    for (int j = 0; j < 2; ++j) async16(a_g[j], a_l0[j]);
#pragma unroll
    for (int j = 0; j < 2; ++j) async16(b_g[j], b_l0[j]);
    for (int kt = 0; kt < KT; ++kt) {
      int cur = kt & 1, nxt = cur ^ 1;
      int curo = cur * 4096, nxto = nxt * 4096;
      if (kt + 1 < KT) {
        int koff = (kt + 1) * 32;
#pragma unroll
        for (int j = 0; j < 2; ++j) async16(a_g[j] + koff, a_l0[j] + nxto);
#pragma unroll
        for (int j = 0; j < 2; ++j) async16(b_g[j] + koff, b_l0[j] + nxto);
        asm volatile("s_waitcnt vmcnt(4)" ::: "memory");
      } else {
        asm volatile("s_waitcnt vmcnt(0)" ::: "memory");
      }
      asm volatile("s_barrier" ::: "memory");
      bf16x8 af[4], bf[4];
#pragma unroll
      for (int mi = 0; mi < 4; ++mi)
        af[mi] = *(const bf16x8*)(As[0] + curo + (wm + mi * 16 + lm) * 32 + slot8);
#pragma unroll
      for (int ni = 0; ni < 4; ++ni)
        bf[ni] = *(const bf16x8*)(Bs[0] + curo + (wn + ni * 16 + lm) * 32 + slot8);
#pragma unroll
      for (int mi = 0; mi < 4; ++mi)
#pragma unroll
        for (int ni = 0; ni < 4; ++ni)
          acc[mi][ni] = mfma16x16x32(af[mi], bf[ni], acc[mi][ni]);
      asm volatile("s_barrier" ::: "memory");
    }
  } else {
    for (int kt = 0; kt < KT; ++kt) {
      if (kt) __syncthreads();
      int koff = kt * 32;
#pragma unroll
      for (int j = 0; j < 2; ++j) async16(a_g[j] + koff, a_l0[j]);
#pragma unroll
      for (int j = 0; j < 2; ++j)
        *(bf16x8*)(b_l0[j] + lane * 8) = load8cvt(b_g[j] + koff);
      __syncthreads();
      bf16x8 af[4], bf[4];
#pragma unroll
      for (int mi = 0; mi < 4; ++mi)
        af[mi] = *(const bf16x8*)(As[0] + (wm + mi * 16 + lm) * 32 + slot8);
#pragma unroll
      for (int ni = 0; ni < 4; ++ni)
        bf[ni] = *(const bf16x8*)(Bs[0] + (wn + ni * 16 + lm) * 32 + slot8);
#pragma unroll
      for (int mi = 0; mi < 4; ++mi)
#pragma unroll
        for (int ni = 0; ni < 4; ++ni)
          acc[mi][ni] = mfma16x16x32(af[mi], bf[ni], acc[mi][ni]);
    }
  }
#pragma unroll
  for (int mi = 0; mi < 4; ++mi) {
#pragma unroll
    for (int r = 0; r < 4; ++r) {
      int row = wm + mi * 16 + lq * 4 + r;
      if (m0 + row >= cntE) continue;
      size_t obase = (size_t)(slotbase + m0 + row) * NH + n0 + wn;
#pragma unroll
      for (int ni = 0; ni < 4; ++ni)
        dout[obase + ni * 16 + lm] = (bf16_t)acc[mi][ni][r];
    }
  }
}

// ---------------- combine: weighted sum of 4 routed slots + shared ----------------
__global__ __launch_bounds__(256) void k_combine(const bf16_t* __restrict__ dout,
                                                 const int* __restrict__ sot,
                                                 const float* __restrict__ tkw,
                                                 float* __restrict__ out) {
  int t = blockIdx.x;
  int h0 = threadIdx.x * 8;
  int s0 = sot[t * 4 + 0], s1 = sot[t * 4 + 1], s2 = sot[t * 4 + 2], s3 = sot[t * 4 + 3];
  float w0 = tkw[t * 4 + 0], w1 = tkw[t * 4 + 1], w2 = tkw[t * 4 + 2], w3 = tkw[t * 4 + 3];
  bf16x8 v0 = *(const bf16x8*)(dout + (size_t)s0 * NH + h0);
  bf16x8 v1 = *(const bf16x8*)(dout + (size_t)s1 * NH + h0);
  bf16x8 v2 = *(const bf16x8*)(dout + (size_t)s2 * NH + h0);
  bf16x8 v3 = *(const bf16x8*)(dout + (size_t)s3 * NH + h0);
  bf16x8 vs = *(const bf16x8*)(dout + (size_t)(NK * NT + t) * NH + h0);
  float o[8];
#pragma unroll
  for (int j = 0; j < 8; ++j)
    o[j] = w0 * (float)v0[j] + w1 * (float)v1[j] + w2 * (float)v2[j] +
           w3 * (float)v3[j] + (float)vs[j];
  float* op = out + (size_t)t * NH + h0;
  *(float4*)op = make_float4(o[0], o[1], o[2], o[3]);
  *(float4*)(op + 4) = make_float4(o[4], o[5], o[6], o[7]);
}

// ---------------- host launcher ----------------
extern "C" void kernel_launch(void* const* d_in, const int* in_sizes, int n_in,
                              void* d_out, int out_size, void* d_ws, size_t ws_size,
                              hipStream_t stream) {
  const float* x   = (const float*)d_in[0];
  const float* rw  = (const float*)d_in[1];
  const float* eb  = (const float*)d_in[2];
  const float* gup = (const float*)d_in[3];
  const float* dwn = (const float*)d_in[4];
  const float* sg  = (const float*)d_in[5];
  const float* su  = (const float*)d_in[6];
  const float* sd  = (const float*)d_in[7];
  float* out = (float*)d_out;

  char* ws = (char*)d_ws;
  size_t off = 0;
  auto alloc = [&](size_t b) {
    size_t p = off;
    off = (off + b + 255) & ~(size_t)255;
    return p;
  };
  int*    cnt  = (int*)(ws + alloc(NE * 4));
  int*    cnt2 = (int*)(ws + alloc(NE * 4));
  int*    offs = (int*)(ws + alloc((NE + 1) * 4));
  int*    tki  = (int*)(ws + alloc((size_t)NT * NK * 4));
  float*  tkw  = (float*)(ws + alloc((size_t)NT * NK * 4));
  int*    tos  = (int*)(ws + alloc((size_t)NK * NT * 4));
  int*    sot  = (int*)(ws + alloc((size_t)NT * NK * 4));
  bf16_t* xb   = (bf16_t*)(ws + alloc((size_t)NT * NH * 2));
  bf16_t* act  = (bf16_t*)(ws + alloc((size_t)(NK + 1) * NT * NI * 2));
  bf16_t* dob  = (bf16_t*)(ws + alloc((size_t)(NK + 1) * NT * NH * 2));

  bool tierA = (off + (N_GUP + N_DWN + 3 * N_SW) * 2 + 2048) <= ws_size;
  bf16_t *gupb = nullptr, *dwnb = nullptr, *sgb = nullptr, *sub = nullptr, *sdb = nullptr;
  if (tierA) {
    gupb = (bf16_t*)(ws + alloc(N_GUP * 2));
    dwnb = (bf16_t*)(ws + alloc(N_DWN * 2));
    sgb  = (bf16_t*)(ws + alloc(N_SW * 2));
    sub  = (bf16_t*)(ws + alloc(N_SW * 2));
    sdb  = (bf16_t*)(ws + alloc(N_SW * 2));
  }

  hipMemsetAsync(cnt, 0, NE * 4, stream);
  hipMemsetAsync(cnt2, 0, NE * 4, stream);

  if (tierA) {
    long total_vec = (N_GUP + N_DWN + 3 * N_SW) / 8;
    int blocks = (int)((total_vec + 255) / 256);
    k_cvt_all<<<blocks, 256, 0, stream>>>(gup, gupb, dwn, dwnb, sg, sgb, su, sub, sd, sdb);
  }

  k_router<<<NT / 4, 256, 0, stream>>>(x, rw, eb, tki, tkw, cnt, xb);
  k_scan<<<1, 64, 0, stream>>>(cnt, offs);
  k_fill<<<NT / 256, 256, 0, stream>>>(tki, offs, cnt2, tos, sot);

  dim3 gu_grid(16, 12, NE + 1);
  dim3 dn_grid(16, 16, NE + 1);
  if (tierA) {
    k_gateup<bf16_t><<<gu_grid, 256, 0, stream>>>(xb, gupb, sgb, sub, cnt, offs, tos, act);
    k_down<bf16_t><<<dn_grid, 256, 0, stream>>>(act, dwnb, sdb, cnt, offs, dob);
  } else {
    k_gateup<float><<<gu_grid, 256, 0, stream>>>(xb, gup, sg, su, cnt, offs, tos, act);
    k_down<float><<<dn_grid, 256, 0, stream>>>(act, dwn, sd, cnt, offs, dob);
  }

  k_combine<<<NT, 256, 0, stream>>>(dob, sot, tkw, out);
}

// Round 3
// 729.021 us; speedup vs baseline: 1.2863x; 1.0069x over previous
//
#include <hip/hip_runtime.h>
#include <hip/hip_bf16.h>
#include <math.h>
#include <type_traits>

// Problem constants (reference: B=1, S=2048, H=2048, E=16, I=768, top-4, shared I=768)
#define NT 2048   // tokens
#define NH 2048   // hidden
#define NE 16     // routed experts
#define NI 768    // expert intermediate (= shared intermediate)
#define NK 4      // top-k

#define N_GUP ((long)NE * 2 * NI * NH)   // 50331648
#define N_DWN ((long)NE * NH * NI)       // 25165824
#define N_SW  ((long)NI * NH)            // 1572864

typedef __bf16 bf16_t;
typedef __attribute__((ext_vector_type(8))) __bf16 bf16x8;
typedef __attribute__((ext_vector_type(4))) __bf16 bf16x4;
typedef __attribute__((ext_vector_type(4))) float f32x4;

__device__ __forceinline__ f32x4 mfma16x16x32(bf16x8 a, bf16x8 b, f32x4 c) {
  return __builtin_amdgcn_mfma_f32_16x16x32_bf16(a, b, c, 0, 0, 0);
}

// async global->LDS DMA, 16B per lane; LDS dest = wave-uniform base + lane*16
__device__ __forceinline__ void async16(const bf16_t* g, bf16_t* l) {
  __builtin_amdgcn_global_load_lds(
      (const __attribute__((address_space(1))) void*)g,
      (__attribute__((address_space(3))) void*)l, 16, 0, 0);
}

__device__ __forceinline__ bf16x8 load8cvt(const bf16_t* p) {
  return *(const bf16x8*)p;
}
__device__ __forceinline__ bf16x8 load8cvt(const float* p) {
  float4 a = *(const float4*)p;
  float4 b = *(const float4*)(p + 4);
  bf16x8 o;
  o[0] = (bf16_t)a.x; o[1] = (bf16_t)a.y; o[2] = (bf16_t)a.z; o[3] = (bf16_t)a.w;
  o[4] = (bf16_t)b.x; o[5] = (bf16_t)b.y; o[6] = (bf16_t)b.z; o[7] = (bf16_t)b.w;
  return o;
}

// ---------------- fp32 -> bf16 conversion ----------------
// R7: the old grid-stride version ran a 5-deep 64-bit branch chain PER 8-elem
// vector (VALU-throttled a pure-BW kernel). Now: one uniform branch per BLOCK,
// each block converts one contiguous 2048-elem chunk, no loop.
// Block ranges: gup 24576, dwn 12288, sg/su/sd 768 each -> total 39168.
__global__ __launch_bounds__(256) void k_cvt_all(
    const float* __restrict__ gup, bf16_t* __restrict__ gupb,
    const float* __restrict__ dwn, bf16_t* __restrict__ dwnb,
    const float* __restrict__ sg, bf16_t* __restrict__ sgb,
    const float* __restrict__ su, bf16_t* __restrict__ sub,
    const float* __restrict__ sd, bf16_t* __restrict__ sdb) {
  int b = blockIdx.x;
  const float* s;
  bf16_t* d;
  long off;
  if (b < 24576)      { s = gup; d = gupb; off = (long)b * 2048; }
  else if (b < 36864) { s = dwn; d = dwnb; off = (long)(b - 24576) * 2048; }
  else if (b < 37632) { s = sg;  d = sgb;  off = (long)(b - 36864) * 2048; }
  else if (b < 38400) { s = su;  d = sub;  off = (long)(b - 37632) * 2048; }
  else                { s = sd;  d = sdb;  off = (long)(b - 38400) * 2048; }
  long i = off + (long)threadIdx.x * 8;
  *(bf16x8*)(d + i) = load8cvt(s + i);
}

// ---------------- router: sigmoid + biased top-4 (+ fused x->bf16 cvt) ----------
// 4 tokens per 256-thread block (one wave per token).
__global__ __launch_bounds__(256) void k_router(const float* __restrict__ x,
                                                const float* __restrict__ rw,
                                                const float* __restrict__ eb,
                                                int* __restrict__ tki,
                                                float* __restrict__ tkw,
                                                int* __restrict__ cnt,
                                                bf16_t* __restrict__ xb) {
  int wave = threadIdx.x >> 6, lane = threadIdx.x & 63;
  int t = blockIdx.x * 4 + wave;
  const float* xr = x + (long)t * NH;
  float acc[NE];
#pragma unroll
  for (int e = 0; e < NE; ++e) acc[e] = 0.f;
  for (int it = 0; it < NH / 256; ++it) {
    int h = it * 256 + lane * 4;
    float4 xv = *(const float4*)(xr + h);
    bf16x4 xc;
    xc[0] = (bf16_t)xv.x; xc[1] = (bf16_t)xv.y; xc[2] = (bf16_t)xv.z; xc[3] = (bf16_t)xv.w;
    *(bf16x4*)(xb + (size_t)t * NH + h) = xc;
#pragma unroll
    for (int e = 0; e < NE; ++e) {
      float4 wv = *(const float4*)(rw + (long)e * NH + h);
      acc[e] += xv.x * wv.x + xv.y * wv.y + xv.z * wv.z + xv.w * wv.w;
    }
  }
#pragma unroll
  for (int e = 0; e < NE; ++e) {
    float v = acc[e];
#pragma unroll
    for (int off = 32; off > 0; off >>= 1) v += __shfl_down(v, off);
    acc[e] = v;
  }
  if (lane == 0) {
    float s[NE], b[NE];
#pragma unroll
    for (int e = 0; e < NE; ++e) {
      s[e] = 1.f / (1.f + __expf(-acc[e]));
      b[e] = s[e] + eb[e];
    }
    int sel[NK];
    float ssum = 0.f;
    unsigned used = 0;
    for (int kk = 0; kk < NK; ++kk) {
      int best = 0;
      float bv = -1e30f;
      for (int e = 0; e < NE; ++e)
        if (!((used >> e) & 1u) && b[e] > bv) { bv = b[e]; best = e; }
      used |= 1u << best;
      sel[kk] = best;
      ssum += s[best];
    }
    float inv = 1.f / (ssum + 1e-20f);
    for (int kk = 0; kk < NK; ++kk) {
      tki[t * NK + kk] = sel[kk];
      tkw[t * NK + kk] = s[sel[kk]] * inv;
      atomicAdd(cnt + sel[kk], 1);
    }
  }
}

// ---------------- exclusive scan over 16 expert counts ----------------
__global__ void k_scan(const int* __restrict__ cnt, int* __restrict__ offs) {
  if (threadIdx.x == 0) {
    int o = 0;
    for (int e = 0; e < NE; ++e) { offs[e] = o; o += cnt[e]; }
    offs[NE] = o;
  }
}

// ---------------- fill compact slot lists ----------------
__global__ __launch_bounds__(256) void k_fill(const int* __restrict__ tki,
                                              const int* __restrict__ offs,
                                              int* __restrict__ cnt2,
                                              int* __restrict__ tos,
                                              int* __restrict__ sot) {
  int t = blockIdx.x * blockDim.x + threadIdx.x;
  if (t >= NT) return;
#pragma unroll
  for (int kk = 0; kk < NK; ++kk) {
    int e = tki[t * NK + kk];
    int pos = atomicAdd(cnt2 + e, 1);
    int slot = offs[e] + pos;
    tos[slot] = t;
    sot[t * NK + kk] = slot;
  }
}

// LDS tile layout (unpadded, required by global_load_lds lane-order writes):
//   row r, chunk slot c (0..3, 8 bf16): offset r*32 + c*8 elems.
//   Source chunk at slot c is cg = c ^ ((r>>1)&3) (XOR swizzle -> <=2-way bank
//   aliasing on fragment ds_read_b128, free per m136).
//
// R6 (XCD work remap): CONFIRMED +1.84x on gateup (263->143us, FETCH 278->165MB).
// R7: (a) gateup chunk padded 408->416 (16-aligned) so no (expert,tn) panel
// group is split across two XCDs' chunks; (b) __launch_bounds__(256,4) pins
// the 4-waves/SIMD register budget (56 VGPR + 64 AGPR = 120 <= 128) so 4
// blocks/CU can be resident; (c) cvt kernel de-VALU'd (see above).

// ---------------- gate-up GEMM + SwiGLU epilogue ----------------
// flat grid 3328 = 8 * 416 (padded from 3264; w >= 3264 exits via tn >= 12).
// work w: tm = w%16, z = (w/16)%17, tn = w/272. z=0 -> shared expert.
// act[slot][NI]: routed slots [0,4T), shared rows [4T,5T).
template <typename WT>
__global__ __launch_bounds__(256, 4) void k_gateup(
    const bf16_t* __restrict__ xb, const WT* __restrict__ gup,
    const WT* __restrict__ sg, const WT* __restrict__ su,
    const int* __restrict__ cnt, const int* __restrict__ offs,
    const int* __restrict__ tos, bf16_t* __restrict__ act) {
  __shared__ __align__(16) bf16_t As[2][128 * 32];   // 128 M-rows
  __shared__ __align__(16) bf16_t Bg[2][64 * 32];    // 64 N-rows (gate)
  __shared__ __align__(16) bf16_t Bu[2][64 * 32];    // 64 N-rows (up)
  // --- bijective chunked XCD remap, 16-aligned chunks (3328 = 8 * 416) ---
  int flat = blockIdx.x;
  int w = (flat & 7) * 416 + (flat >> 3);
  int tm = w & 15;
  int zz = (w >> 4) % 17;
  int tn = w / 272;
  if (tn >= NI / 64) return;                         // pad blocks
  int g = (zz == 0) ? NE : zz - 1;                   // shared expert first in-chunk
  int cntE, slotbase;
  const WT *gp, *up;
  if (g < NE) {
    cntE = cnt[g];
    slotbase = offs[g];
    gp = gup + (size_t)g * 2 * NI * NH;
    up = gp + (size_t)NI * NH;
  } else {
    cntE = NT;
    slotbase = NK * NT;
    gp = sg;
    up = su;
  }
  int m0 = tm * 128;
  if (m0 >= cntE) return;
  int n0 = tn * 64;
  int tid = threadIdx.x;
  int wave = tid >> 6, lane = tid & 63;
  int lrow = lane >> 2;                       // 0..15 in a 16-row issue
  int cg = (lane & 3) ^ ((lane >> 3) & 3);    // swizzled source chunk

  // A staging: 8 wave-issues of 16 rows; wave w handles issues 2w, 2w+1.
  const bf16_t* a_g[2];
  bf16_t* a_l0[2];                            // buffer-0 dest; buffer 1 = +4096
#pragma unroll
  for (int j = 0; j < 2; ++j) {
    int rb = (wave * 2 + j) * 16;
    int r = rb + lrow;
    int tok;
    if (g < NE)
      tok = (m0 + r < cntE) ? tos[slotbase + m0 + r] : 0;
    else
      tok = m0 + r;
    a_g[j] = xb + (size_t)tok * NH + cg * 8;
    a_l0[j] = As[0] + rb * 32;
  }
  // B staging: 2 matrices x 4 issues = 8; wave w handles issues 2w, 2w+1.
  const WT* b_g[2];
  bf16_t* b_l0[2];                            // buffer 1 = +2048
#pragma unroll
  for (int j = 0; j < 2; ++j) {
    int idx = wave * 2 + j;
    int mat = idx >> 2;
    int rb = (idx & 3) * 16;
    int r = rb + lrow;
    b_g[j] = (mat ? up : gp) + (size_t)(n0 + r) * NH + cg * 8;
    b_l0[j] = (mat ? Bu[0] : Bg[0]) + rb * 32;
  }

  f32x4 zero = {0.f, 0.f, 0.f, 0.f};
  f32x4 accg[4][2], accu[4][2];
#pragma unroll
  for (int mi = 0; mi < 4; ++mi)
#pragma unroll
    for (int ni = 0; ni < 2; ++ni) {
      accg[mi][ni] = zero;
      accu[mi][ni] = zero;
    }
  int wm = (wave >> 1) * 64, wn = (wave & 1) * 32;
  int lm = lane & 15, lq = lane >> 4;
  int slot8 = (lq ^ ((lm >> 1) & 3)) * 8;     // fragment-read chunk slot
  const int KT = NH / 32;

  if constexpr (std::is_same<WT, bf16_t>::value) {
    // prologue: tile 0 -> buffer 0
#pragma unroll
    for (int j = 0; j < 2; ++j) async16(a_g[j], a_l0[j]);
#pragma unroll
    for (int j = 0; j < 2; ++j) async16(b_g[j], b_l0[j]);
    for (int kt = 0; kt < KT; ++kt) {
      int cur = kt & 1, nxt = cur ^ 1;
      int curoA = cur * 4096, curoB = cur * 2048;
      if (kt + 1 < KT) {
        int koff = (kt + 1) * 32;
        int nxtoA = nxt * 4096, nxtoB = nxt * 2048;
#pragma unroll
        for (int j = 0; j < 2; ++j) async16(a_g[j] + koff, a_l0[j] + nxtoA);
#pragma unroll
        for (int j = 0; j < 2; ++j) async16(b_g[j] + koff, b_l0[j] + nxtoB);
        asm volatile("s_waitcnt vmcnt(4)" ::: "memory");  // tile kt landed; kt+1 in flight
      } else {
        asm volatile("s_waitcnt vmcnt(0)" ::: "memory");
      }
      asm volatile("s_barrier" ::: "memory");
      bf16x8 af[4], bg[2], bu[2];
#pragma unroll
      for (int mi = 0; mi < 4; ++mi)
        af[mi] = *(const bf16x8*)(As[0] + curoA + (wm + mi * 16 + lm) * 32 + slot8);
#pragma unroll
      for (int ni = 0; ni < 2; ++ni) {
        bg[ni] = *(const bf16x8*)(Bg[0] + curoB + (wn + ni * 16 + lm) * 32 + slot8);
        bu[ni] = *(const bf16x8*)(Bu[0] + curoB + (wn + ni * 16 + lm) * 32 + slot8);
      }
#pragma unroll
      for (int mi = 0; mi < 4; ++mi)
#pragma unroll
        for (int ni = 0; ni < 2; ++ni) {
          accg[mi][ni] = mfma16x16x32(af[mi], bg[ni], accg[mi][ni]);
          accu[mi][ni] = mfma16x16x32(af[mi], bu[ni], accu[mi][ni]);
        }
      asm volatile("s_barrier" ::: "memory");  // readers done before kt+2 overwrites cur
    }
  } else {
    // fp32-weight fallback: single-buffered, register staging for B
    for (int kt = 0; kt < KT; ++kt) {
      if (kt) __syncthreads();
      int koff = kt * 32;
#pragma unroll
      for (int j = 0; j < 2; ++j) async16(a_g[j] + koff, a_l0[j]);
#pragma unroll
      for (int j = 0; j < 2; ++j)
        *(bf16x8*)(b_l0[j] + lane * 8) = load8cvt(b_g[j] + koff);
      __syncthreads();
      bf16x8 af[4], bg[2], bu[2];
#pragma unroll
      for (int mi = 0; mi < 4; ++mi)
        af[mi] = *(const bf16x8*)(As[0] + (wm + mi * 16 + lm) * 32 + slot8);
#pragma unroll
      for (int ni = 0; ni < 2; ++ni) {
        bg[ni] = *(const bf16x8*)(Bg[0] + (wn + ni * 16 + lm) * 32 + slot8);
        bu[ni] = *(const bf16x8*)(Bu[0] + (wn + ni * 16 + lm) * 32 + slot8);
      }
#pragma unroll
      for (int mi = 0; mi < 4; ++mi)
#pragma unroll
        for (int ni = 0; ni < 2; ++ni) {
          accg[mi][ni] = mfma16x16x32(af[mi], bg[ni], accg[mi][ni]);
          accu[mi][ni] = mfma16x16x32(af[mi], bu[ni], accu[mi][ni]);
        }
    }
  }
  // SwiGLU epilogue: act = silu(g) * u   (C/D layout: col=lane&15, row=quad*4+reg)
#pragma unroll
  for (int mi = 0; mi < 4; ++mi) {
#pragma unroll
    for (int r = 0; r < 4; ++r) {
      int row = wm + mi * 16 + lq * 4 + r;
      if (m0 + row >= cntE) continue;
      size_t obase = (size_t)(slotbase + m0 + row) * NI + n0 + wn;
#pragma unroll
      for (int ni = 0; ni < 2; ++ni) {
        float gv = accg[mi][ni][r];
        float uv = accu[mi][ni][r];
        float a = gv / (1.f + __expf(-gv)) * uv;
        act[obase + ni * 16 + lm] = (bf16_t)a;
      }
    }
  }
}

// ---------------- down GEMM ----------------
// flat grid 4352 = 8 * 544 (544 = 34 complete 16-block panel groups).
// w: tm = w%16, z = (w/16)%17, tn = w/272. Writes dout[slot][NH] (bf16).
template <typename WT>
__global__ __launch_bounds__(256, 4) void k_down(
    const bf16_t* __restrict__ act, const WT* __restrict__ dwn,
    const WT* __restrict__ sd, const int* __restrict__ cnt,
    const int* __restrict__ offs, bf16_t* __restrict__ dout) {
  __shared__ __align__(16) bf16_t As[2][128 * 32];
  __shared__ __align__(16) bf16_t Bs[2][128 * 32];
  int flat = blockIdx.x;
  int w = (flat & 7) * 544 + (flat >> 3);
  int tm = w & 15;
  int zz = (w >> 4) % 17;
  int tn = w / 272;
  int g = (zz == 0) ? NE : zz - 1;
  int cntE, slotbase;
  const WT* wp;
  if (g < NE) {
    cntE = cnt[g];
    slotbase = offs[g];
    wp = dwn + (size_t)g * NH * NI;
  } else {
    cntE = NT;
    slotbase = NK * NT;
    wp = sd;
  }
  int m0 = tm * 128;
  if (m0 >= cntE) return;
  int n0 = tn * 128;
  int tid = threadIdx.x;
  int wave = tid >> 6, lane = tid & 63;
  int lrow = lane >> 2;
  int cg = (lane & 3) ^ ((lane >> 3) & 3);

  const bf16_t* a_g[2];
  bf16_t* a_l0[2];
  const WT* b_g[2];
  bf16_t* b_l0[2];
#pragma unroll
  for (int j = 0; j < 2; ++j) {
    int rb = (wave * 2 + j) * 16;
    int r = rb + lrow;
    a_g[j] = act + (size_t)(slotbase + m0 + r) * NI + cg * 8;
    a_l0[j] = As[0] + rb * 32;
    b_g[j] = wp + (size_t)(n0 + r) * NI + cg * 8;
    b_l0[j] = Bs[0] + rb * 32;
  }
  f32x4 zero = {0.f, 0.f, 0.f, 0.f};
  f32x4 acc[4][4];
#pragma unroll
  for (int mi = 0; mi < 4; ++mi)
#pragma unroll
    for (int ni = 0; ni < 4; ++ni) acc[mi][ni] = zero;
  int wm = (wave >> 1) * 64, wn = (wave & 1) * 64;
  int lm = lane & 15, lq = lane >> 4;
  int slot8 = (lq ^ ((lm >> 1) & 3)) * 8;
  const int KT = NI / 32;

  if constexpr (std::is_same<WT, bf16_t>::value) {
#pragma unroll
    for (int j = 0; j < 2; ++j) async16(a_g[j], a_l0[j]);
#pragma unroll
    for (int j = 0; j < 2; ++j) async16(b_g[j], b_l0[j]);
    for (int kt = 0; kt < KT; ++kt) {
      int cur = kt & 1, nxt = cur ^ 1;
      int curo = cur * 4096, nxto = nxt * 4096;
      if (kt + 1 < KT) {
        int koff = (kt + 1) * 32;
#pragma unroll
        for (int j = 0; j < 2; ++j) async16(a_g[j] + koff, a_l0[j] + nxto);
#pragma unroll
        for (int j = 0; j < 2; ++j) async16(b_g[j] + koff, b_l0[j] + nxto);
        asm volatile("s_waitcnt vmcnt(4)" ::: "memory");
      } else {
        asm volatile("s_waitcnt vmcnt(0)" ::: "memory");
      }
      asm volatile("s_barrier" ::: "memory");
      bf16x8 af[4], bf[4];
#pragma unroll
      for (int mi = 0; mi < 4; ++mi)
        af[mi] = *(const bf16x8*)(As[0] + curo + (wm + mi * 16 + lm) * 32 + slot8);
#pragma unroll
      for (int ni = 0; ni < 4; ++ni)
        bf[ni] = *(const bf16x8*)(Bs[0] + curo + (wn + ni * 16 + lm) * 32 + slot8);
#pragma unroll
      for (int mi = 0; mi < 4; ++mi)
#pragma unroll
        for (int ni = 0; ni < 4; ++ni)
          acc[mi][ni] = mfma16x16x32(af[mi], bf[ni], acc[mi][ni]);
      asm volatile("s_barrier" ::: "memory");
    }
  } else {
    for (int kt = 0; kt < KT; ++kt) {
      if (kt) __syncthreads();
      int koff = kt * 32;
#pragma unroll
      for (int j = 0; j < 2; ++j) async16(a_g[j] + koff, a_l0[j]);
#pragma unroll
      for (int j = 0; j < 2; ++j)
        *(bf16x8*)(b_l0[j] + lane * 8) = load8cvt(b_g[j] + koff);
      __syncthreads();
      bf16x8 af[4], bf[4];
#pragma unroll
      for (int mi = 0; mi < 4; ++mi)
        af[mi] = *(const bf16x8*)(As[0] + (wm + mi * 16 + lm) * 32 + slot8);
#pragma unroll
      for (int ni = 0; ni < 4; ++ni)
        bf[ni] = *(const bf16x8*)(Bs[0] + (wn + ni * 16 + lm) * 32 + slot8);
#pragma unroll
      for (int mi = 0; mi < 4; ++mi)
#pragma unroll
        for (int ni = 0; ni < 4; ++ni)
          acc[mi][ni] = mfma16x16x32(af[mi], bf[ni], acc[mi][ni]);
    }
  }
#pragma unroll
  for (int mi = 0; mi < 4; ++mi) {
#pragma unroll
    for (int r = 0; r < 4; ++r) {
      int row = wm + mi * 16 + lq * 4 + r;
      if (m0 + row >= cntE) continue;
      size_t obase = (size_t)(slotbase + m0 + row) * NH + n0 + wn;
#pragma unroll
      for (int ni = 0; ni < 4; ++ni)
        dout[obase + ni * 16 + lm] = (bf16_t)acc[mi][ni][r];
    }
  }
}

// ---------------- combine: weighted sum of 4 routed slots + shared ----------------
__global__ __launch_bounds__(256) void k_combine(const bf16_t* __restrict__ dout,
                                                 const int* __restrict__ sot,
                                                 const float* __restrict__ tkw,
                                                 float* __restrict__ out) {
  int t = blockIdx.x;
  int h0 = threadIdx.x * 8;
  int s0 = sot[t * 4 + 0], s1 = sot[t * 4 + 1], s2 = sot[t * 4 + 2], s3 = sot[t * 4 + 3];
  float w0 = tkw[t * 4 + 0], w1 = tkw[t * 4 + 1], w2 = tkw[t * 4 + 2], w3 = tkw[t * 4 + 3];
  bf16x8 v0 = *(const bf16x8*)(dout + (size_t)s0 * NH + h0);
  bf16x8 v1 = *(const bf16x8*)(dout + (size_t)s1 * NH + h0);
  bf16x8 v2 = *(const bf16x8*)(dout + (size_t)s2 * NH + h0);
  bf16x8 v3 = *(const bf16x8*)(dout + (size_t)s3 * NH + h0);
  bf16x8 vs = *(const bf16x8*)(dout + (size_t)(NK * NT + t) * NH + h0);
  float o[8];
#pragma unroll
  for (int j = 0; j < 8; ++j)
    o[j] = w0 * (float)v0[j] + w1 * (float)v1[j] + w2 * (float)v2[j] +
           w3 * (float)v3[j] + (float)vs[j];
  float* op = out + (size_t)t * NH + h0;
  *(float4*)op = make_float4(o[0], o[1], o[2], o[3]);
  *(float4*)(op + 4) = make_float4(o[4], o[5], o[6], o[7]);
}

// ---------------- host launcher ----------------
extern "C" void kernel_launch(void* const* d_in, const int* in_sizes, int n_in,
                              void* d_out, int out_size, void* d_ws, size_t ws_size,
                              hipStream_t stream) {
  const float* x   = (const float*)d_in[0];
  const float* rw  = (const float*)d_in[1];
  const float* eb  = (const float*)d_in[2];
  const float* gup = (const float*)d_in[3];
  const float* dwn = (const float*)d_in[4];
  const float* sg  = (const float*)d_in[5];
  const float* su  = (const float*)d_in[6];
  const float* sd  = (const float*)d_in[7];
  float* out = (float*)d_out;

  char* ws = (char*)d_ws;
  size_t off = 0;
  auto alloc = [&](size_t b) {
    size_t p = off;
    off = (off + b + 255) & ~(size_t)255;
    return p;
  };
  int*    cnt  = (int*)(ws + alloc(NE * 4));
  int*    cnt2 = (int*)(ws + alloc(NE * 4));
  int*    offs = (int*)(ws + alloc((NE + 1) * 4));
  int*    tki  = (int*)(ws + alloc((size_t)NT * NK * 4));
  float*  tkw  = (float*)(ws + alloc((size_t)NT * NK * 4));
  int*    tos  = (int*)(ws + alloc((size_t)NK * NT * 4));
  int*    sot  = (int*)(ws + alloc((size_t)NT * NK * 4));
  bf16_t* xb   = (bf16_t*)(ws + alloc((size_t)NT * NH * 2));
  bf16_t* act  = (bf16_t*)(ws + alloc((size_t)(NK + 1) * NT * NI * 2));
  bf16_t* dob  = (bf16_t*)(ws + alloc((size_t)(NK + 1) * NT * NH * 2));

  bool tierA = (off + (N_GUP + N_DWN + 3 * N_SW) * 2 + 2048) <= ws_size;
  bf16_t *gupb = nullptr, *dwnb = nullptr, *sgb = nullptr, *sub = nullptr, *sdb = nullptr;
  if (tierA) {
    gupb = (bf16_t*)(ws + alloc(N_GUP * 2));
    dwnb = (bf16_t*)(ws + alloc(N_DWN * 2));
    sgb  = (bf16_t*)(ws + alloc(N_SW * 2));
    sub  = (bf16_t*)(ws + alloc(N_SW * 2));
    sdb  = (bf16_t*)(ws + alloc(N_SW * 2));
  }

  hipMemsetAsync(cnt, 0, NE * 4, stream);
  hipMemsetAsync(cnt2, 0, NE * 4, stream);

  if (tierA) {
    k_cvt_all<<<39168, 256, 0, stream>>>(gup, gupb, dwn, dwnb, sg, sgb, su, sub, sd, sdb);
  }

  k_router<<<NT / 4, 256, 0, stream>>>(x, rw, eb, tki, tkw, cnt, xb);
  k_scan<<<1, 64, 0, stream>>>(cnt, offs);
  k_fill<<<NT / 256, 256, 0, stream>>>(tki, offs, cnt2, tos, sot);

  if (tierA) {
    k_gateup<bf16_t><<<3328, 256, 0, stream>>>(xb, gupb, sgb, sub, cnt, offs, tos, act);
    k_down<bf16_t><<<4352, 256, 0, stream>>>(act, dwnb, sdb, cnt, offs, dob);
  } else {
    k_gateup<float><<<3328, 256, 0, stream>>>(xb, gup, sg, su, cnt, offs, tos, act);
    k_down<float><<<4352, 256, 0, stream>>>(act, dwn, sd, cnt, offs, dob);
  }

  k_combine<<<NT, 256, 0, stream>>>(dob, sot, tkw, out);
}

// Round 4
// 696.850 us; speedup vs baseline: 1.3457x; 1.0462x over previous
//
#include <hip/hip_runtime.h>
#include <hip/hip_bf16.h>
#include <math.h>
#include <type_traits>

// Problem constants (reference: B=1, S=2048, H=2048, E=16, I=768, top-4, shared I=768)
#define NT 2048   // tokens
#define NH 2048   // hidden
#define NE 16     // routed experts
#define NI 768    // expert intermediate (= shared intermediate)
#define NK 4      // top-k

#define N_GUP ((long)NE * 2 * NI * NH)   // 50331648
#define N_DWN ((long)NE * NH * NI)       // 25165824
#define N_SW  ((long)NI * NH)            // 1572864

typedef __bf16 bf16_t;
typedef __attribute__((ext_vector_type(8))) __bf16 bf16x8;
typedef __attribute__((ext_vector_type(4))) __bf16 bf16x4;
typedef __attribute__((ext_vector_type(4))) float f32x4;

__device__ __forceinline__ f32x4 mfma16x16x32(bf16x8 a, bf16x8 b, f32x4 c) {
  return __builtin_amdgcn_mfma_f32_16x16x32_bf16(a, b, c, 0, 0, 0);
}

// async global->LDS DMA, 16B per lane; LDS dest = wave-uniform base + lane*16
__device__ __forceinline__ void async16(const bf16_t* g, bf16_t* l) {
  __builtin_amdgcn_global_load_lds(
      (const __attribute__((address_space(1))) void*)g,
      (__attribute__((address_space(3))) void*)l, 16, 0, 0);
}

__device__ __forceinline__ bf16x8 load8cvt(const bf16_t* p) {
  return *(const bf16x8*)p;
}
__device__ __forceinline__ bf16x8 load8cvt(const float* p) {
  float4 a = *(const float4*)p;
  float4 b = *(const float4*)(p + 4);
  bf16x8 o;
  o[0] = (bf16_t)a.x; o[1] = (bf16_t)a.y; o[2] = (bf16_t)a.z; o[3] = (bf16_t)a.w;
  o[4] = (bf16_t)b.x; o[5] = (bf16_t)b.y; o[6] = (bf16_t)b.z; o[7] = (bf16_t)b.w;
  return o;
}

// ---------------- fp32 -> bf16 conversion ----------------
// One uniform branch per BLOCK, each block converts one contiguous 2048-elem
// chunk. Block ranges: gup 24576, dwn 12288, sg/su/sd 768 each -> 39168.
__global__ __launch_bounds__(256) void k_cvt_all(
    const float* __restrict__ gup, bf16_t* __restrict__ gupb,
    const float* __restrict__ dwn, bf16_t* __restrict__ dwnb,
    const float* __restrict__ sg, bf16_t* __restrict__ sgb,
    const float* __restrict__ su, bf16_t* __restrict__ sub,
    const float* __restrict__ sd, bf16_t* __restrict__ sdb) {
  int b = blockIdx.x;
  const float* s;
  bf16_t* d;
  long off;
  if (b < 24576)      { s = gup; d = gupb; off = (long)b * 2048; }
  else if (b < 36864) { s = dwn; d = dwnb; off = (long)(b - 24576) * 2048; }
  else if (b < 37632) { s = sg;  d = sgb;  off = (long)(b - 36864) * 2048; }
  else if (b < 38400) { s = su;  d = sub;  off = (long)(b - 37632) * 2048; }
  else                { s = sd;  d = sdb;  off = (long)(b - 38400) * 2048; }
  long i = off + (long)threadIdx.x * 8;
  *(bf16x8*)(d + i) = load8cvt(s + i);
}

// ---------------- router: sigmoid + biased top-4 (+ fused x->bf16 cvt) ----------
// 4 tokens per 256-thread block (one wave per token).
__global__ __launch_bounds__(256) void k_router(const float* __restrict__ x,
                                                const float* __restrict__ rw,
                                                const float* __restrict__ eb,
                                                int* __restrict__ tki,
                                                float* __restrict__ tkw,
                                                int* __restrict__ cnt,
                                                bf16_t* __restrict__ xb) {
  int wave = threadIdx.x >> 6, lane = threadIdx.x & 63;
  int t = blockIdx.x * 4 + wave;
  const float* xr = x + (long)t * NH;
  float acc[NE];
#pragma unroll
  for (int e = 0; e < NE; ++e) acc[e] = 0.f;
  for (int it = 0; it < NH / 256; ++it) {
    int h = it * 256 + lane * 4;
    float4 xv = *(const float4*)(xr + h);
    bf16x4 xc;
    xc[0] = (bf16_t)xv.x; xc[1] = (bf16_t)xv.y; xc[2] = (bf16_t)xv.z; xc[3] = (bf16_t)xv.w;
    *(bf16x4*)(xb + (size_t)t * NH + h) = xc;
#pragma unroll
    for (int e = 0; e < NE; ++e) {
      float4 wv = *(const float4*)(rw + (long)e * NH + h);
      acc[e] += xv.x * wv.x + xv.y * wv.y + xv.z * wv.z + xv.w * wv.w;
    }
  }
#pragma unroll
  for (int e = 0; e < NE; ++e) {
    float v = acc[e];
#pragma unroll
    for (int off = 32; off > 0; off >>= 1) v += __shfl_down(v, off);
    acc[e] = v;
  }
  if (lane == 0) {
    float s[NE], b[NE];
#pragma unroll
    for (int e = 0; e < NE; ++e) {
      s[e] = 1.f / (1.f + __expf(-acc[e]));
      b[e] = s[e] + eb[e];
    }
    int sel[NK];
    float ssum = 0.f;
    unsigned used = 0;
    for (int kk = 0; kk < NK; ++kk) {
      int best = 0;
      float bv = -1e30f;
      for (int e = 0; e < NE; ++e)
        if (!((used >> e) & 1u) && b[e] > bv) { bv = b[e]; best = e; }
      used |= 1u << best;
      sel[kk] = best;
      ssum += s[best];
    }
    float inv = 1.f / (ssum + 1e-20f);
    for (int kk = 0; kk < NK; ++kk) {
      tki[t * NK + kk] = sel[kk];
      tkw[t * NK + kk] = s[sel[kk]] * inv;
      atomicAdd(cnt + sel[kk], 1);
    }
  }
}

// ---------------- fused scan + fill (LDS counters, single block) ----------------
__global__ __launch_bounds__(1024) void k_fillscan(const int* __restrict__ cnt,
                                                   const int* __restrict__ tki,
                                                   int* __restrict__ offs,
                                                   int* __restrict__ tos,
                                                   int* __restrict__ sot) {
  __shared__ int soffs[NE + 1];
  __shared__ int scnt[NE];
  int tid = threadIdx.x;
  if (tid == 0) {
    int o = 0;
    for (int e = 0; e < NE; ++e) { soffs[e] = o; o += cnt[e]; }
    soffs[NE] = o;
  }
  if (tid < NE) scnt[tid] = 0;
  __syncthreads();
  if (tid < NE + 1) offs[tid] = soffs[tid];
  for (int t = tid; t < NT; t += 1024) {
#pragma unroll
    for (int kk = 0; kk < NK; ++kk) {
      int e = tki[t * NK + kk];
      int pos = atomicAdd(&scnt[e], 1);
      int slot = soffs[e] + pos;
      tos[slot] = t;
      sot[t * NK + kk] = slot;
    }
  }
}

// LDS tile layout (unpadded, required by global_load_lds lane-order writes):
//   row r, chunk slot c (0..3, 8 bf16): offset r*32 + c*8 elems.
//   Source chunk at slot c is cg = c ^ ((r>>1)&3) (XOR swizzle -> <=2-way bank
//   aliasing on fragment ds_read_b128, free per m136).
//
// R6 (XCD remap): CONFIRMED +1.84x on gateup (263->143us, FETCH 278->165MB).
// R8 (depth-3 retest IN the new regime): R5 tested pipeline depth pre-remap,
// when the L3 path was queue-saturated (~3.5 TB/s) -> null was regime-invalid.
// Post-remap: HBM 16%, MfmaUtil 20%, occ 21% -> latency-bound with idle BW.
// 1-tile-ahead prefetch covers L2 (~200cy) but not L3/HBM (~600-900cy) loads.
// Now: 3 LDS buffers, 2 tiles in flight, steady-state vmcnt(8) (never drained
// mid-loop), 4->0 epilogue. 48KB LDS caps 3 blocks/CU -- non-binding (avg
// residency measured ~1.7).

// ---------------- gate-up GEMM + SwiGLU epilogue ----------------
// flat grid 3328 = 8 * 416 (16-aligned chunks; w >= 3264 exits via tn >= 12).
// work w: tm = w%16, z = (w/16)%17, tn = w/272. z=0 -> shared expert.
// act[slot][NI]: routed slots [0,4T), shared rows [4T,5T).
template <typename WT>
__global__ __launch_bounds__(256, 3) void k_gateup(
    const bf16_t* __restrict__ xb, const WT* __restrict__ gup,
    const WT* __restrict__ sg, const WT* __restrict__ su,
    const int* __restrict__ cnt, const int* __restrict__ offs,
    const int* __restrict__ tos, bf16_t* __restrict__ act) {
  __shared__ __align__(16) bf16_t As[3][128 * 32];   // 128 M-rows, 3-stage
  __shared__ __align__(16) bf16_t Bg[3][64 * 32];    // 64 N-rows (gate)
  __shared__ __align__(16) bf16_t Bu[3][64 * 32];    // 64 N-rows (up)
  int flat = blockIdx.x;
  int w = (flat & 7) * 416 + (flat >> 3);
  int tm = w & 15;
  int zz = (w >> 4) % 17;
  int tn = w / 272;
  if (tn >= NI / 64) return;                         // pad blocks
  int g = (zz == 0) ? NE : zz - 1;                   // shared expert first in-chunk
  int cntE, slotbase;
  const WT *gp, *up;
  if (g < NE) {
    cntE = cnt[g];
    slotbase = offs[g];
    gp = gup + (size_t)g * 2 * NI * NH;
    up = gp + (size_t)NI * NH;
  } else {
    cntE = NT;
    slotbase = NK * NT;
    gp = sg;
    up = su;
  }
  int m0 = tm * 128;
  if (m0 >= cntE) return;
  int n0 = tn * 64;
  int tid = threadIdx.x;
  int wave = tid >> 6, lane = tid & 63;
  int lrow = lane >> 2;                       // 0..15 in a 16-row issue
  int cg = (lane & 3) ^ ((lane >> 3) & 3);    // swizzled source chunk

  // A staging: 8 wave-issues of 16 rows; wave w handles issues 2w, 2w+1.
  const bf16_t* a_g[2];
  bf16_t* a_l0[2];                            // buffer b = +b*4096 elems
#pragma unroll
  for (int j = 0; j < 2; ++j) {
    int rb = (wave * 2 + j) * 16;
    int r = rb + lrow;
    int tok;
    if (g < NE)
      tok = (m0 + r < cntE) ? tos[slotbase + m0 + r] : 0;
    else
      tok = m0 + r;
    a_g[j] = xb + (size_t)tok * NH + cg * 8;
    a_l0[j] = As[0] + rb * 32;
  }
  // B staging: 2 matrices x 4 issues = 8; wave w handles issues 2w, 2w+1.
  const WT* b_g[2];
  bf16_t* b_l0[2];                            // buffer b = +b*2048 elems
#pragma unroll
  for (int j = 0; j < 2; ++j) {
    int idx = wave * 2 + j;
    int mat = idx >> 2;
    int rb = (idx & 3) * 16;
    int r = rb + lrow;
    b_g[j] = (mat ? up : gp) + (size_t)(n0 + r) * NH + cg * 8;
    b_l0[j] = (mat ? Bu[0] : Bg[0]) + rb * 32;
  }

  f32x4 zero = {0.f, 0.f, 0.f, 0.f};
  f32x4 accg[4][2], accu[4][2];
#pragma unroll
  for (int mi = 0; mi < 4; ++mi)
#pragma unroll
    for (int ni = 0; ni < 2; ++ni) {
      accg[mi][ni] = zero;
      accu[mi][ni] = zero;
    }
  int wm = (wave >> 1) * 64, wn = (wave & 1) * 32;
  int lm = lane & 15, lq = lane >> 4;
  int slot8 = (lq ^ ((lm >> 1) & 3)) * 8;     // fragment-read chunk slot
  const int KT = NH / 32;

  if constexpr (std::is_same<WT, bf16_t>::value) {
    // prologue: tiles 0,1 -> buffers 0,1 (8 loads/wave in flight)
#pragma unroll
    for (int j = 0; j < 2; ++j) async16(a_g[j], a_l0[j]);
#pragma unroll
    for (int j = 0; j < 2; ++j) async16(b_g[j], b_l0[j]);
#pragma unroll
    for (int j = 0; j < 2; ++j) async16(a_g[j] + 32, a_l0[j] + 4096);
#pragma unroll
    for (int j = 0; j < 2; ++j) async16(b_g[j] + 32, b_l0[j] + 2048);
    int cur = 0, nb = 2;                      // buffer rotation
    for (int kt = 0; kt < KT; ++kt) {
      int curoA = cur * 4096, curoB = cur * 2048;
      if (kt + 2 < KT) {
        int koff = (kt + 2) * 32;
        int nA = nb * 4096, nB = nb * 2048;
#pragma unroll
        for (int j = 0; j < 2; ++j) async16(a_g[j] + koff, a_l0[j] + nA);
#pragma unroll
        for (int j = 0; j < 2; ++j) async16(b_g[j] + koff, b_l0[j] + nB);
        // tiles kt+1, kt+2 (8 loads) stay in flight across the barrier
        asm volatile("s_waitcnt vmcnt(8)" ::: "memory");
      } else if (kt + 1 < KT) {
        asm volatile("s_waitcnt vmcnt(4)" ::: "memory");
      } else {
        asm volatile("s_waitcnt vmcnt(0)" ::: "memory");
      }
      asm volatile("s_barrier" ::: "memory");  // all waves' tile-kt loads landed
      bf16x8 af[4], bg[2], bu[2];
#pragma unroll
      for (int mi = 0; mi < 4; ++mi)
        af[mi] = *(const bf16x8*)(As[0] + curoA + (wm + mi * 16 + lm) * 32 + slot8);
#pragma unroll
      for (int ni = 0; ni < 2; ++ni) {
        bg[ni] = *(const bf16x8*)(Bg[0] + curoB + (wn + ni * 16 + lm) * 32 + slot8);
        bu[ni] = *(const bf16x8*)(Bu[0] + curoB + (wn + ni * 16 + lm) * 32 + slot8);
      }
#pragma unroll
      for (int mi = 0; mi < 4; ++mi)
#pragma unroll
        for (int ni = 0; ni < 2; ++ni) {
          accg[mi][ni] = mfma16x16x32(af[mi], bg[ni], accg[mi][ni]);
          accu[mi][ni] = mfma16x16x32(af[mi], bu[ni], accu[mi][ni]);
        }
      // readers done before tile kt+3 (issued next iter) overwrites buf cur
      asm volatile("s_barrier" ::: "memory");
      cur = (cur == 2) ? 0 : cur + 1;
      nb = (nb == 2) ? 0 : nb + 1;
    }
  } else {
    // fp32-weight fallback: single-buffered, register staging for B
    for (int kt = 0; kt < KT; ++kt) {
      if (kt) __syncthreads();
      int koff = kt * 32;
#pragma unroll
      for (int j = 0; j < 2; ++j) async16(a_g[j] + koff, a_l0[j]);
#pragma unroll
      for (int j = 0; j < 2; ++j)
        *(bf16x8*)(b_l0[j] + lane * 8) = load8cvt(b_g[j] + koff);
      __syncthreads();
      bf16x8 af[4], bg[2], bu[2];
#pragma unroll
      for (int mi = 0; mi < 4; ++mi)
        af[mi] = *(const bf16x8*)(As[0] + (wm + mi * 16 + lm) * 32 + slot8);
#pragma unroll
      for (int ni = 0; ni < 2; ++ni) {
        bg[ni] = *(const bf16x8*)(Bg[0] + (wn + ni * 16 + lm) * 32 + slot8);
        bu[ni] = *(const bf16x8*)(Bu[0] + (wn + ni * 16 + lm) * 32 + slot8);
      }
#pragma unroll
      for (int mi = 0; mi < 4; ++mi)
#pragma unroll
        for (int ni = 0; ni < 2; ++ni) {
          accg[mi][ni] = mfma16x16x32(af[mi], bg[ni], accg[mi][ni]);
          accu[mi][ni] = mfma16x16x32(af[mi], bu[ni], accu[mi][ni]);
        }
    }
  }
  // SwiGLU epilogue: act = silu(g) * u   (C/D layout: col=lane&15, row=quad*4+reg)
#pragma unroll
  for (int mi = 0; mi < 4; ++mi) {
#pragma unroll
    for (int r = 0; r < 4; ++r) {
      int row = wm + mi * 16 + lq * 4 + r;
      if (m0 + row >= cntE) continue;
      size_t obase = (size_t)(slotbase + m0 + row) * NI + n0 + wn;
#pragma unroll
      for (int ni = 0; ni < 2; ++ni) {
        float gv = accg[mi][ni][r];
        float uv = accu[mi][ni][r];
        float a = gv / (1.f + __expf(-gv)) * uv;
        act[obase + ni * 16 + lm] = (bf16_t)a;
      }
    }
  }
}

// ---------------- down GEMM ----------------
// flat grid 4352 = 8 * 544 (34 complete 16-block panel groups per XCD chunk).
// w: tm = w%16, z = (w/16)%17, tn = w/272. Writes dout[slot][NH] (bf16).
template <typename WT>
__global__ __launch_bounds__(256, 3) void k_down(
    const bf16_t* __restrict__ act, const WT* __restrict__ dwn,
    const WT* __restrict__ sd, const int* __restrict__ cnt,
    const int* __restrict__ offs, bf16_t* __restrict__ dout) {
  __shared__ __align__(16) bf16_t As[3][128 * 32];
  __shared__ __align__(16) bf16_t Bs[3][128 * 32];
  int flat = blockIdx.x;
  int w = (flat & 7) * 544 + (flat >> 3);
  int tm = w & 15;
  int zz = (w >> 4) % 17;
  int tn = w / 272;
  int g = (zz == 0) ? NE : zz - 1;
  int cntE, slotbase;
  const WT* wp;
  if (g < NE) {
    cntE = cnt[g];
    slotbase = offs[g];
    wp = dwn + (size_t)g * NH * NI;
  } else {
    cntE = NT;
    slotbase = NK * NT;
    wp = sd;
  }
  int m0 = tm * 128;
  if (m0 >= cntE) return;
  int n0 = tn * 128;
  int tid = threadIdx.x;
  int wave = tid >> 6, lane = tid & 63;
  int lrow = lane >> 2;
  int cg = (lane & 3) ^ ((lane >> 3) & 3);

  const bf16_t* a_g[2];
  bf16_t* a_l0[2];
  const WT* b_g[2];
  bf16_t* b_l0[2];
#pragma unroll
  for (int j = 0; j < 2; ++j) {
    int rb = (wave * 2 + j) * 16;
    int r = rb + lrow;
    a_g[j] = act + (size_t)(slotbase + m0 + r) * NI + cg * 8;
    a_l0[j] = As[0] + rb * 32;
    b_g[j] = wp + (size_t)(n0 + r) * NI + cg * 8;
    b_l0[j] = Bs[0] + rb * 32;
  }
  f32x4 zero = {0.f, 0.f, 0.f, 0.f};
  f32x4 acc[4][4];
#pragma unroll
  for (int mi = 0; mi < 4; ++mi)
#pragma unroll
    for (int ni = 0; ni < 4; ++ni) acc[mi][ni] = zero;
  int wm = (wave >> 1) * 64, wn = (wave & 1) * 64;
  int lm = lane & 15, lq = lane >> 4;
  int slot8 = (lq ^ ((lm >> 1) & 3)) * 8;
  const int KT = NI / 32;

  if constexpr (std::is_same<WT, bf16_t>::value) {
    // prologue: tiles 0,1 -> buffers 0,1
#pragma unroll
    for (int j = 0; j < 2; ++j) async16(a_g[j], a_l0[j]);
#pragma unroll
    for (int j = 0; j < 2; ++j) async16(b_g[j], b_l0[j]);
#pragma unroll
    for (int j = 0; j < 2; ++j) async16(a_g[j] + 32, a_l0[j] + 4096);
#pragma unroll
    for (int j = 0; j < 2; ++j) async16(b_g[j] + 32, b_l0[j] + 4096);
    int cur = 0, nb = 2;
    for (int kt = 0; kt < KT; ++kt) {
      int curo = cur * 4096;
      if (kt + 2 < KT) {
        int koff = (kt + 2) * 32;
        int nA = nb * 4096;
#pragma unroll
        for (int j = 0; j < 2; ++j) async16(a_g[j] + koff, a_l0[j] + nA);
#pragma unroll
        for (int j = 0; j < 2; ++j) async16(b_g[j] + koff, b_l0[j] + nA);
        asm volatile("s_waitcnt vmcnt(8)" ::: "memory");
      } else if (kt + 1 < KT) {
        asm volatile("s_waitcnt vmcnt(4)" ::: "memory");
      } else {
        asm volatile("s_waitcnt vmcnt(0)" ::: "memory");
      }
      asm volatile("s_barrier" ::: "memory");
      bf16x8 af[4], bf[4];
#pragma unroll
      for (int mi = 0; mi < 4; ++mi)
        af[mi] = *(const bf16x8*)(As[0] + curo + (wm + mi * 16 + lm) * 32 + slot8);
#pragma unroll
      for (int ni = 0; ni < 4; ++ni)
        bf[ni] = *(const bf16x8*)(Bs[0] + curo + (wn + ni * 16 + lm) * 32 + slot8);
#pragma unroll
      for (int mi = 0; mi < 4; ++mi)
#pragma unroll
        for (int ni = 0; ni < 4; ++ni)
          acc[mi][ni] = mfma16x16x32(af[mi], bf[ni], acc[mi][ni]);
      asm volatile("s_barrier" ::: "memory");
      cur = (cur == 2) ? 0 : cur + 1;
      nb = (nb == 2) ? 0 : nb + 1;
    }
  } else {
    for (int kt = 0; kt < KT; ++kt) {
      if (kt) __syncthreads();
      int koff = kt * 32;
#pragma unroll
      for (int j = 0; j < 2; ++j) async16(a_g[j] + koff, a_l0[j]);
#pragma unroll
      for (int j = 0; j < 2; ++j)
        *(bf16x8*)(b_l0[j] + lane * 8) = load8cvt(b_g[j] + koff);
      __syncthreads();
      bf16x8 af[4], bf[4];
#pragma unroll
      for (int mi = 0; mi < 4; ++mi)
        af[mi] = *(const bf16x8*)(As[0] + (wm + mi * 16 + lm) * 32 + slot8);
#pragma unroll
      for (int ni = 0; ni < 4; ++ni)
        bf[ni] = *(const bf16x8*)(Bs[0] + (wn + ni * 16 + lm) * 32 + slot8);
#pragma unroll
      for (int mi = 0; mi < 4; ++mi)
#pragma unroll
        for (int ni = 0; ni < 4; ++ni)
          acc[mi][ni] = mfma16x16x32(af[mi], bf[ni], acc[mi][ni]);
    }
  }
#pragma unroll
  for (int mi = 0; mi < 4; ++mi) {
#pragma unroll
    for (int r = 0; r < 4; ++r) {
      int row = wm + mi * 16 + lq * 4 + r;
      if (m0 + row >= cntE) continue;
      size_t obase = (size_t)(slotbase + m0 + row) * NH + n0 + wn;
#pragma unroll
      for (int ni = 0; ni < 4; ++ni)
        dout[obase + ni * 16 + lm] = (bf16_t)acc[mi][ni][r];
    }
  }
}

// ---------------- combine: weighted sum of 4 routed slots + shared ----------------
__global__ __launch_bounds__(256) void k_combine(const bf16_t* __restrict__ dout,
                                                 const int* __restrict__ sot,
                                                 const float* __restrict__ tkw,
                                                 float* __restrict__ out) {
  int t = blockIdx.x;
  int h0 = threadIdx.x * 8;
  int s0 = sot[t * 4 + 0], s1 = sot[t * 4 + 1], s2 = sot[t * 4 + 2], s3 = sot[t * 4 + 3];
  float w0 = tkw[t * 4 + 0], w1 = tkw[t * 4 + 1], w2 = tkw[t * 4 + 2], w3 = tkw[t * 4 + 3];
  bf16x8 v0 = *(const bf16x8*)(dout + (size_t)s0 * NH + h0);
  bf16x8 v1 = *(const bf16x8*)(dout + (size_t)s1 * NH + h0);
  bf16x8 v2 = *(const bf16x8*)(dout + (size_t)s2 * NH + h0);
  bf16x8 v3 = *(const bf16x8*)(dout + (size_t)s3 * NH + h0);
  bf16x8 vs = *(const bf16x8*)(dout + (size_t)(NK * NT + t) * NH + h0);
  float o[8];
#pragma unroll
  for (int j = 0; j < 8; ++j)
    o[j] = w0 * (float)v0[j] + w1 * (float)v1[j] + w2 * (float)v2[j] +
           w3 * (float)v3[j] + (float)vs[j];
  float* op = out + (size_t)t * NH + h0;
  *(float4*)op = make_float4(o[0], o[1], o[2], o[3]);
  *(float4*)(op + 4) = make_float4(o[4], o[5], o[6], o[7]);
}

// ---------------- host launcher ----------------
extern "C" void kernel_launch(void* const* d_in, const int* in_sizes, int n_in,
                              void* d_out, int out_size, void* d_ws, size_t ws_size,
                              hipStream_t stream) {
  const float* x   = (const float*)d_in[0];
  const float* rw  = (const float*)d_in[1];
  const float* eb  = (const float*)d_in[2];
  const float* gup = (const float*)d_in[3];
  const float* dwn = (const float*)d_in[4];
  const float* sg  = (const float*)d_in[5];
  const float* su  = (const float*)d_in[6];
  const float* sd  = (const float*)d_in[7];
  float* out = (float*)d_out;

  char* ws = (char*)d_ws;
  size_t off = 0;
  auto alloc = [&](size_t b) {
    size_t p = off;
    off = (off + b + 255) & ~(size_t)255;
    return p;
  };
  int*    cnt  = (int*)(ws + alloc(NE * 4));
  int*    offs = (int*)(ws + alloc((NE + 1) * 4));
  int*    tki  = (int*)(ws + alloc((size_t)NT * NK * 4));
  float*  tkw  = (float*)(ws + alloc((size_t)NT * NK * 4));
  int*    tos  = (int*)(ws + alloc((size_t)NK * NT * 4));
  int*    sot  = (int*)(ws + alloc((size_t)NT * NK * 4));
  bf16_t* xb   = (bf16_t*)(ws + alloc((size_t)NT * NH * 2));
  bf16_t* act  = (bf16_t*)(ws + alloc((size_t)(NK + 1) * NT * NI * 2));
  bf16_t* dob  = (bf16_t*)(ws + alloc((size_t)(NK + 1) * NT * NH * 2));

  bool tierA = (off + (N_GUP + N_DWN + 3 * N_SW) * 2 + 2048) <= ws_size;
  bf16_t *gupb = nullptr, *dwnb = nullptr, *sgb = nullptr, *sub = nullptr, *sdb = nullptr;
  if (tierA) {
    gupb = (bf16_t*)(ws + alloc(N_GUP * 2));
    dwnb = (bf16_t*)(ws + alloc(N_DWN * 2));
    sgb  = (bf16_t*)(ws + alloc(N_SW * 2));
    sub  = (bf16_t*)(ws + alloc(N_SW * 2));
    sdb  = (bf16_t*)(ws + alloc(N_SW * 2));
  }

  hipMemsetAsync(cnt, 0, NE * 4, stream);

  if (tierA) {
    k_cvt_all<<<39168, 256, 0, stream>>>(gup, gupb, dwn, dwnb, sg, sgb, su, sub, sd, sdb);
  }

  k_router<<<NT / 4, 256, 0, stream>>>(x, rw, eb, tki, tkw, cnt, xb);
  k_fillscan<<<1, 1024, 0, stream>>>(cnt, tki, offs, tos, sot);

  if (tierA) {
    k_gateup<bf16_t><<<3328, 256, 0, stream>>>(xb, gupb, sgb, sub, cnt, offs, tos, act);
    k_down<bf16_t><<<4352, 256, 0, stream>>>(act, dwnb, sdb, cnt, offs, dob);
  } else {
    k_gateup<float><<<3328, 256, 0, stream>>>(xb, gup, sg, su, cnt, offs, tos, act);
    k_down<float><<<4352, 256, 0, stream>>>(act, dwn, sd, cnt, offs, dob);
  }

  k_combine<<<NT, 256, 0, stream>>>(dob, sot, tkw, out);
}